// Round 13
// baseline (357.040 us; speedup 1.0000x reference)
//
#include <hip/hip_runtime.h>

#define CDIM 768
#define BATCH 8
#define LDEPTH 8
#define HHEIGHT 14
#define WWIDTH 14
#define NSP 1568      // 8*14*14 spatial tokens (input / q)
#define NSPX 1576     // lin-buffer row stride: NSP + cls col (1568) + pad
#define NQTOK 1569    // +cls
#define NKSP 392      // 8*7*7 spatial tokens (k/v after pool)
#define NKTOK 393
#define NHEADS 12
#define HEADDIM 64
#define ATTN_SCALE 0.125f
#define LN_EPS 1e-6f
#define MTOK (BATCH * NQTOK)   // 12552 tokens for proj GEMM
#define NPAD_X 1792            // Xt padded rows per batch (7 tiles * 256)
#define WELEM (CDIM * CDIM)    // 589824
#define TQP 1792               // padded q tokens per (b,h)  (7*256)
#define TKP 448                // padded kv tokens per (b,h) (7*64)

typedef _Float16 f16;
typedef _Float16 f16x8_t __attribute__((ext_vector_type(8)));
typedef _Float16 f16x4_t __attribute__((ext_vector_type(4)));
typedef float f32x4_t __attribute__((ext_vector_type(4)));
typedef float f32x2_t __attribute__((ext_vector_type(2)));

// global -> LDS direct 16B copy (wave-uniform LDS base + lane*16)
__device__ __forceinline__ void gld_lds16(const void* g, void* l) {
  __builtin_amdgcn_global_load_lds(
      (const __attribute__((address_space(1))) void*)g,
      (__attribute__((address_space(3))) void*)l, 16, 0, 0);
}

// ---------------------------------------------------------------------------
// fp32 -> fp16 convert for the 4 weight matrices (one launch, grid.y = mat)
// ---------------------------------------------------------------------------
__global__ __launch_bounds__(256) void convert4_kernel(
    const float* __restrict__ s0, const float* __restrict__ s1,
    const float* __restrict__ s2, const float* __restrict__ s3,
    f16* __restrict__ dst) {
  const int mat = blockIdx.y;
  const float* src = (mat == 0) ? s0 : (mat == 1) ? s1 : (mat == 2) ? s2 : s3;
  int i = (blockIdx.x * 256 + threadIdx.x) * 4;
  if (i < WELEM) {
    float4 v = *(const float4*)&src[i];
    f16x4_t h = {(f16)v.x, (f16)v.y, (f16)v.z, (f16)v.w};
    *(f16x4_t*)&dst[(size_t)mat * WELEM + i] = h;
  }
}

// ---------------------------------------------------------------------------
// Transpose+convert X: (B,768,1568) f32 -> Xt (B,1792,768) f16.
// Row 1568 = class_token; rows >1568 = 0.
// ---------------------------------------------------------------------------
__global__ __launch_bounds__(256) void transpose_x_kernel(
    const float* __restrict__ X, const float* __restrict__ cls,
    f16* __restrict__ Xt) {
  __shared__ float t[32][33];
  const int b = blockIdx.z;
  const int k0 = blockIdx.y * 32;
  const int n0 = blockIdx.x * 32;   // grid.x = 56 (1792/32)
  const int tx = threadIdx.x & 31, ty = threadIdx.x >> 5;
#pragma unroll
  for (int i = 0; i < 4; i++) {
    int k = k0 + ty + i * 8;
    int n = n0 + tx;
    float v;
    if (n < NSP)
      v = X[((size_t)b * CDIM + k) * NSP + n];
    else if (n == NSP)
      v = cls[b * CDIM + k];
    else
      v = 0.f;
    t[ty + i * 8][tx] = v;
  }
  __syncthreads();
#pragma unroll
  for (int i = 0; i < 4; i++) {
    int n = n0 + ty + i * 8;
    Xt[((size_t)b * NPAD_X + n) * CDIM + k0 + tx] = (f16)t[tx][ty + i * 8];
  }
}

// ---------------------------------------------------------------------------
// Fused QKV MFMA GEMM. Block tile 128(m) x 256(n), BK=32, 4 waves, wave tile
// 64x128 (acc[4][8]). A-fragments read DIRECTLY from global (L2-hot weights,
// register-prefetched one K-step ahead; vmcnt drain at the barrier retires
// them with B staging). B staged via global_load_lds with source-side XOR
// swizzle matched by read-side XOR. LDS/K-step: 48 KB (was 72).
// 1D grid 1008, XCD swizzle: batch = bid&7.
// ---------------------------------------------------------------------------
__global__ __launch_bounds__(256, 2) void gemm_qkv_f16_kernel(
    const f16* __restrict__ W16, const f16* __restrict__ Xt,
    const float* __restrict__ bq, const float* __restrict__ bk,
    const float* __restrict__ bv, f16* __restrict__ OutBase) {
  __shared__ __align__(16) f16 Bsm[256 * 32];   // 16 KB

  const int bid = blockIdx.x;
  const int b = bid & 7;
  const int rem = bid >> 3;
  const int mat = rem / 42;
  const int rem2 = rem % 42;
  const int m0 = (rem2 / 7) * 128;
  const int n0 = (rem2 % 7) * 256;
  const int tid = threadIdx.x;
  const int lane = tid & 63;
  const int w = tid >> 6;
  const int wr = w >> 1, wc = w & 1;
  const int l15 = lane & 15, l4 = lane >> 4;

  const f16* A16 = W16 + (size_t)mat * WELEM;
  const float* bias = (mat == 0) ? bq : (mat == 1) ? bk : bv;
  f16* Out = OutBase + (size_t)mat * ((size_t)BATCH * CDIM * NSPX);

  // B staging: wave w rows [w*64, w*64+64), lane -> row w*64+(lane>>2),
  // k-chunk source-swizzled.
  const int srow = lane >> 2;
  const int skq = ((lane & 3) ^ ((lane >> 3) & 3)) * 8;
  const f16* Bg = Xt + ((size_t)b * NPAD_X + n0 + w * 64 + srow) * CDIM + skq;
  f16* lB = Bsm + w * 64 * 32;

  const int rsw = (l15 >> 1) & 3;
  const int kchunk = (l4 ^ rsw) * 8;

  // A fragment base: row m0 + wr*64 + mi*16 + l15, k = k0 + l4*8 (no swizzle)
  const f16* Afrag = A16 + (size_t)(m0 + wr * 64 + l15) * CDIM + l4 * 8;

  f32x4_t acc[4][8];
#pragma unroll
  for (int i = 0; i < 4; i++)
#pragma unroll
    for (int j = 0; j < 8; j++) acc[i][j] = (f32x4_t){0.f, 0.f, 0.f, 0.f};

  f16x8_t afc[4], afn[4];
#pragma unroll
  for (int mi = 0; mi < 4; mi++)
    afc[mi] = *(const f16x8_t*)(Afrag + (size_t)(mi * 16) * CDIM);

  for (int t = 0; t < CDIM / 32; ++t) {
    const int k0 = t * 32;
    gld_lds16(Bg + k0, lB);
    gld_lds16(Bg + 16 * CDIM + k0, lB + 16 * 32);
    gld_lds16(Bg + 32 * CDIM + k0, lB + 32 * 32);
    gld_lds16(Bg + 48 * CDIM + k0, lB + 48 * 32);
    if (t + 1 < CDIM / 32) {
#pragma unroll
      for (int mi = 0; mi < 4; mi++)
        afn[mi] =
            *(const f16x8_t*)(Afrag + (size_t)(mi * 16) * CDIM + k0 + 32);
    }
    __syncthreads();   // vmcnt(0) drain: B staged AND afn in regs
#pragma unroll
    for (int ni = 0; ni < 8; ni++) {
      f16x8_t bfv =
          *(const f16x8_t*)(Bsm + (wc * 128 + ni * 16 + l15) * 32 + kchunk);
#pragma unroll
      for (int mi = 0; mi < 4; mi++)
        acc[mi][ni] = __builtin_amdgcn_mfma_f32_16x16x32_f16(
            afc[mi], bfv, acc[mi][ni], 0, 0, 0);
    }
    __syncthreads();   // B reads done before next staging overwrite
#pragma unroll
    for (int mi = 0; mi < 4; mi++) afc[mi] = afn[mi];
  }

#pragma unroll
  for (int mi = 0; mi < 4; mi++) {
    const int mbase = m0 + wr * 64 + mi * 16 + l4 * 4;
#pragma unroll
    for (int ni = 0; ni < 8; ni++) {
      const int n = n0 + wc * 128 + ni * 16 + l15;
      if (n < NQTOK) {   // n == 1568 is the cls column
#pragma unroll
        for (int r = 0; r < 4; r++) {
          Out[((size_t)b * CDIM + mbase + r) * NSPX + n] =
              (f16)(acc[mi][ni][r] + bias[mbase + r]);
        }
      }
    }
  }
}

// ---------------------------------------------------------------------------
// Projection MFMA GEMM, same A-from-global structure. 1D grid 300, bijective
// XCD swizzle (nwg=300: q=37, r=4).
// ---------------------------------------------------------------------------
__global__ __launch_bounds__(256, 2) void gemm_proj_f16_kernel(
    const f16* __restrict__ Wp16, const f16* __restrict__ o16,
    const float* __restrict__ bias, float* __restrict__ xo,
    float* __restrict__ cls_o) {
  __shared__ __align__(16) f16 Bsm[256 * 32];

  const int bid = blockIdx.x;
  const int xcd = bid & 7, pos_ = bid >> 3;
  const int base = (xcd < 4) ? xcd * 38 : 152 + (xcd - 4) * 37;
  const int wgid = base + pos_;
  const int m0 = (wgid / 50) * 128;
  const int n0 = (wgid % 50) * 256;
  const int tid = threadIdx.x;
  const int lane = tid & 63;
  const int w = tid >> 6;
  const int wr = w >> 1, wc = w & 1;
  const int l15 = lane & 15, l4 = lane >> 4;

  const int srow = lane >> 2;
  const int skq = ((lane & 3) ^ ((lane >> 3) & 3)) * 8;
  const f16* Bg = o16 + (size_t)(n0 + w * 64 + srow) * CDIM + skq;
  f16* lB = Bsm + w * 64 * 32;

  const int rsw = (l15 >> 1) & 3;
  const int kchunk = (l4 ^ rsw) * 8;

  const f16* Afrag = Wp16 + (size_t)(m0 + wr * 64 + l15) * CDIM + l4 * 8;

  f32x4_t acc[4][8];
#pragma unroll
  for (int i = 0; i < 4; i++)
#pragma unroll
    for (int j = 0; j < 8; j++) acc[i][j] = (f32x4_t){0.f, 0.f, 0.f, 0.f};

  f16x8_t afc[4], afn[4];
#pragma unroll
  for (int mi = 0; mi < 4; mi++)
    afc[mi] = *(const f16x8_t*)(Afrag + (size_t)(mi * 16) * CDIM);

  for (int t = 0; t < CDIM / 32; ++t) {
    const int k0 = t * 32;
    gld_lds16(Bg + k0, lB);
    gld_lds16(Bg + 16 * CDIM + k0, lB + 16 * 32);
    gld_lds16(Bg + 32 * CDIM + k0, lB + 32 * 32);
    gld_lds16(Bg + 48 * CDIM + k0, lB + 48 * 32);
    if (t + 1 < CDIM / 32) {
#pragma unroll
      for (int mi = 0; mi < 4; mi++)
        afn[mi] =
            *(const f16x8_t*)(Afrag + (size_t)(mi * 16) * CDIM + k0 + 32);
    }
    __syncthreads();
#pragma unroll
    for (int ni = 0; ni < 8; ni++) {
      f16x8_t bfv =
          *(const f16x8_t*)(Bsm + (wc * 128 + ni * 16 + l15) * 32 + kchunk);
#pragma unroll
      for (int mi = 0; mi < 4; mi++)
        acc[mi][ni] = __builtin_amdgcn_mfma_f32_16x16x32_f16(
            afc[mi], bfv, acc[mi][ni], 0, 0, 0);
    }
    __syncthreads();
#pragma unroll
    for (int mi = 0; mi < 4; mi++) afc[mi] = afn[mi];
  }

#pragma unroll
  for (int ni = 0; ni < 8; ni++) {
    const int tok = n0 + wc * 128 + ni * 16 + l15;
    if (tok < MTOK) {
      const int bb = tok / NQTOK;
      const int nn = tok % NQTOK;
#pragma unroll
      for (int mi = 0; mi < 4; mi++) {
        const int mbase = m0 + wr * 64 + mi * 16 + l4 * 4;
#pragma unroll
        for (int r = 0; r < 4; r++) {
          float v = acc[mi][ni][r] + bias[mbase + r];
          if (nn == 0)
            cls_o[bb * CDIM + mbase + r] = v;
          else
            xo[((size_t)bb * CDIM + mbase + r) * (size_t)NSP + nn - 1] = v;
        }
      }
    }
  }
}

// ---------------------------------------------------------------------------
// Depthwise conv for q (stride 1, out 8x14x14). One block per (b,c) plane.
// L-fastest padded LDS volume (round-12 verified).
// ---------------------------------------------------------------------------
__global__ __launch_bounds__(256) void dwconv_q_kernel(
    const f16* __restrict__ q_lin, const float* __restrict__ cq,
    f16* __restrict__ q_pool) {
  __shared__ float vol[16 * 196];   // 12,544 B
  __shared__ float wsm[27];
  const int c = blockIdx.x % CDIM;
  const int b = blockIdx.x / CDIM;
  const f16* xb = q_lin + ((size_t)b * CDIM + c) * (size_t)NSPX;

  for (int i = threadIdx.x; i < 16 * 196; i += 256) vol[i] = 0.f;
  if (threadIdx.x < 27) wsm[threadIdx.x] = cq[c * 27 + threadIdx.x];
  __syncthreads();
  for (int i = threadIdx.x; i < NSP; i += 256) {
    int li = i / 196;
    int r = i - li * 196;
    int hi = r / 14;
    int wi = r - hi * 14;
    vol[(wi + 1) * 196 + (hi + 1) * 12 + (li + 1)] = (float)xb[i];
  }
  __syncthreads();

  if (threadIdx.x < 196) {
    const int ho = threadIdx.x / 14;
    const int wo = threadIdx.x - ho * 14;
    float sums[8];
#pragma unroll
    for (int lo = 0; lo < 8; lo++) sums[lo] = 0.f;
#pragma unroll
    for (int kh = 0; kh < 3; kh++) {
#pragma unroll
      for (int kw = 0; kw < 3; kw++) {
        const float* p = &vol[(wo + kw) * 196 + (ho + kh) * 12];
        float z[10];
        *(f32x4_t*)&z[0] = *(const f32x4_t*)p;
        *(f32x4_t*)&z[4] = *(const f32x4_t*)(p + 4);
        *(f32x2_t*)&z[8] = *(const f32x2_t*)(p + 8);
        const float w0 = wsm[0 + kh * 3 + kw];
        const float w1 = wsm[9 + kh * 3 + kw];
        const float w2 = wsm[18 + kh * 3 + kw];
#pragma unroll
        for (int lo = 0; lo < 8; lo++) {
          sums[lo] = fmaf(z[lo], w0, sums[lo]);
          sums[lo] = fmaf(z[lo + 1], w1, sums[lo]);
          sums[lo] = fmaf(z[lo + 2], w2, sums[lo]);
        }
      }
    }
    f16* ob = q_pool + ((size_t)b * CDIM + c) * (size_t)NSP;
    const int hw = ho * 14 + wo;
#pragma unroll
    for (int lo = 0; lo < 8; lo++) ob[lo * 196 + hw] = (f16)sums[lo];
  }
}

// ---------------------------------------------------------------------------
// Depthwise conv for k/v (stride 2, out 8x7x7). 4 channels per block.
// ---------------------------------------------------------------------------
__global__ __launch_bounds__(256) void dwconv_kv_kernel(
    const f16* __restrict__ k_lin, const f16* __restrict__ v_lin,
    const float* __restrict__ ck, const float* __restrict__ cv,
    f16* __restrict__ k_pool, f16* __restrict__ v_pool) {
  __shared__ float vol4[4][16 * 196];   // 50,176 B
  __shared__ float wsm4[4][27];
  const int which = blockIdx.y;
  const f16* X = which ? v_lin : k_lin;
  const float* wconv = which ? cv : ck;
  f16* Out = which ? v_pool : k_pool;
  const int cg = blockIdx.x % (CDIM / 4);
  const int b = blockIdx.x / (CDIM / 4);
  const int c0 = cg * 4;
  const f16* xb0 = X + ((size_t)b * CDIM + c0) * (size_t)NSPX;

  for (int i = threadIdx.x; i < 4 * 16 * 196; i += 256)
    ((float*)vol4)[i] = 0.f;
  if (threadIdx.x < 108) {
    int ch = threadIdx.x / 27;
    int j = threadIdx.x - ch * 27;
    wsm4[ch][j] = wconv[(c0 + ch) * 27 + j];
  }
  __syncthreads();
  for (int i = threadIdx.x; i < 4 * NSP; i += 256) {
    int ch = i / NSP;
    int j = i - ch * NSP;
    int li = j / 196;
    int r = j - li * 196;
    int hi = r / 14;
    int wi = r - hi * 14;
    vol4[ch][(wi + 1) * 196 + (hi + 1) * 12 + (li + 1)] =
        (float)xb0[(size_t)ch * NSPX + j];
  }
  __syncthreads();

  if (threadIdx.x < 196) {
    const int ch = threadIdx.x / 49;
    const int p2 = threadIdx.x - ch * 49;
    const int ho = p2 / 7;
    const int wo = p2 - ho * 7;
    const float* vol = vol4[ch];
    const float* wsm = wsm4[ch];
    float sums[8];
#pragma unroll
    for (int lo = 0; lo < 8; lo++) sums[lo] = 0.f;
#pragma unroll
    for (int kh = 0; kh < 3; kh++) {
#pragma unroll
      for (int kw = 0; kw < 3; kw++) {
        const float* p = &vol[(wo * 2 + kw) * 196 + (ho * 2 + kh) * 12];
        float z[10];
        *(f32x4_t*)&z[0] = *(const f32x4_t*)p;
        *(f32x4_t*)&z[4] = *(const f32x4_t*)(p + 4);
        *(f32x2_t*)&z[8] = *(const f32x2_t*)(p + 8);
        const float w0 = wsm[0 + kh * 3 + kw];
        const float w1 = wsm[9 + kh * 3 + kw];
        const float w2 = wsm[18 + kh * 3 + kw];
#pragma unroll
        for (int lo = 0; lo < 8; lo++) {
          sums[lo] = fmaf(z[lo], w0, sums[lo]);
          sums[lo] = fmaf(z[lo + 1], w1, sums[lo]);
          sums[lo] = fmaf(z[lo + 2], w2, sums[lo]);
        }
      }
    }
    f16* ob = Out + ((size_t)b * CDIM + c0 + ch) * (size_t)NKSP;
    const int hw = ho * 7 + wo;
#pragma unroll
    for (int lo = 0; lo < 8; lo++) ob[lo * 49 + hw] = (f16)sums[lo];
  }
}

// ---------------------------------------------------------------------------
// Fused LayerNorm + head-pack for q AND k in one launch: grid (62, B).
// ---------------------------------------------------------------------------
__global__ __launch_bounds__(256) void ln_pack_qk2_kernel(
    const f16* __restrict__ qp, const f16* __restrict__ kp,
    const float* __restrict__ lnq_w, const float* __restrict__ lnq_b,
    const float* __restrict__ lnk_w, const float* __restrict__ lnk_b,
    f16* __restrict__ Qh, f16* __restrict__ Kh) {
  const int bx = blockIdx.x;
  const bool isq = bx < 49;
  const f16* xp = isq ? qp : kp;
  const float* ln_w = isq ? lnq_w : lnk_w;
  const float* ln_b = isq ? lnq_b : lnk_b;
  f16* OutH = isq ? Qh : Kh;
  const int np = isq ? NSP : NKSP;
  const int tp = isq ? TQP : TKP;
  const int b = blockIdx.y;
  const int p0 = (isq ? bx : bx - 49) * 32;
  const int tid = threadIdx.x;
  const int pl = tid & 31;
  const int grp = tid >> 5;
  const int pos = p0 + pl;
  const bool act = pos < np;
  const f16* Xb = xp + (size_t)b * CDIM * (size_t)np;

  __shared__ __align__(16) f16 tile[32][784];
  __shared__ float r1[8][33], r2[8][33];
  __shared__ float smean[32], srstd[32];

  const int swz = (pl & 7) << 3;
  float s1 = 0.f, s2 = 0.f;
  for (int cc = 0; cc < 12; cc++) {
    const int c0 = grp * 96 + cc * 8;
    f16x8_t hv;
#pragma unroll
    for (int i = 0; i < 8; i++) {
      f16 h = act ? Xb[(size_t)(c0 + i) * np + pos] : (f16)0.f;
      hv[i] = h;
      float v = (float)h;
      s1 += v;
      s2 = fmaf(v, v, s2);
    }
    *(f16x8_t*)&tile[pl][c0 ^ swz] = hv;
  }
  r1[grp][pl] = s1;
  r2[grp][pl] = s2;
  __syncthreads();
  if (tid < 32) {
    float t1 = 0.f, t2 = 0.f;
#pragma unroll
    for (int g = 0; g < 8; g++) { t1 += r1[g][tid]; t2 += r2[g][tid]; }
    float mean = t1 * (1.f / 768.f);
    float var = t2 * (1.f / 768.f) - mean * mean;
    smean[tid] = mean;
    srstd[tid] = rsqrtf(var + LN_EPS);
  }
  __syncthreads();

  const int tl = tid >> 3, d8 = (tid & 7) * 8;
  const float mean = smean[tl], rstd = srstd[tl];
  const bool wv = (p0 + tl) < np;
  const int tswz = (tl & 7) << 3;
#pragma unroll
  for (int h = 0; h < NHEADS; h++) {
    const int c = h * 64 + d8;
    f16x8_t raw = *(const f16x8_t*)&tile[tl][c ^ tswz];
    float4 w1 = *(const float4*)&ln_w[c];
    float4 w2 = *(const float4*)&ln_w[c + 4];
    float4 b1 = *(const float4*)&ln_b[c];
    float4 b2 = *(const float4*)&ln_b[c + 4];
    f16x8_t ov;
    ov[0] = (f16)(((float)raw[0] - mean) * rstd * w1.x + b1.x);
    ov[1] = (f16)(((float)raw[1] - mean) * rstd * w1.y + b1.y);
    ov[2] = (f16)(((float)raw[2] - mean) * rstd * w1.z + b1.z);
    ov[3] = (f16)(((float)raw[3] - mean) * rstd * w1.w + b1.w);
    ov[4] = (f16)(((float)raw[4] - mean) * rstd * w2.x + b2.x);
    ov[5] = (f16)(((float)raw[5] - mean) * rstd * w2.y + b2.y);
    ov[6] = (f16)(((float)raw[6] - mean) * rstd * w2.z + b2.z);
    ov[7] = (f16)(((float)raw[7] - mean) * rstd * w2.w + b2.w);
    if (wv)
      *(uint4*)(OutH +
                (((size_t)(b * NHEADS + h)) * (size_t)tp + (p0 + tl + 1)) * 64 +
                d8) = *(uint4*)&ov;
  }
}

// ---------------------------------------------------------------------------
// Fused LayerNorm + transpose-pack for v. cls (t=0) raw from v_lin col NSP.
// ---------------------------------------------------------------------------
__global__ __launch_bounds__(256) void ln_pack_v_kernel(
    const f16* __restrict__ vp, const f16* __restrict__ vlin,
    const float* __restrict__ ln_w, const float* __restrict__ ln_b,
    f16* __restrict__ Vht) {
  const int b = blockIdx.y;
  const int t0 = blockIdx.x * 32;
  const int tid = threadIdx.x;
  const int pl = tid & 31;
  const int grp = tid >> 5;
  const int t = t0 + pl;
  const int pos = t - 1;
  const bool isv = (t >= 1) && (t < NKTOK);
  const f16* Vb = vp + (size_t)b * CDIM * (size_t)NKSP;

  __shared__ float r1[8][33], r2[8][33];
  __shared__ float smean[32], srstd[32];
  __shared__ __align__(16) f16 vtile[128][40];

  float s1 = 0.f, s2 = 0.f;
  if (isv) {
    for (int c = grp; c < CDIM; c += 8) {
      float v = (float)Vb[(size_t)c * NKSP + pos];
      s1 += v;
      s2 = fmaf(v, v, s2);
    }
  }
  r1[grp][pl] = s1;
  r2[grp][pl] = s2;
  __syncthreads();
  if (tid < 32) {
    float t1 = 0.f, t2 = 0.f;
#pragma unroll
    for (int g = 0; g < 8; g++) { t1 += r1[g][tid]; t2 += r2[g][tid]; }
    float mean = t1 * (1.f / 768.f);
    float var = t2 * (1.f / 768.f) - mean * mean;
    smean[tid] = mean;
    srstd[tid] = rsqrtf(var + LN_EPS);
  }
  __syncthreads();
  const float mean = smean[pl], rstd = srstd[pl];

  for (int cc = 0; cc < 6; cc++) {
#pragma unroll
    for (int i = 0; i < 16; i++) {
      int cl = grp * 16 + i;
      int c = cc * 128 + cl;
      float outv;
      if (isv)
        outv = ((float)Vb[(size_t)c * NKSP + pos] - mean) * rstd * ln_w[c] +
               ln_b[c];
      else if (t == 0)
        outv = (float)vlin[((size_t)b * CDIM + c) * NSPX + NSP];
      else
        outv = 0.f;
      vtile[cl][pl] = (f16)outv;
    }
    __syncthreads();
#pragma unroll
    for (int it = 0; it < 2; it++) {
      int idx = it * 256 + tid;
      int cl = idx >> 2, t8 = (idx & 3) * 8;
      uint4 vv = *(const uint4*)&vtile[cl][t8];
      *(uint4*)(Vht + ((size_t)b * CDIM + cc * 128 + cl) * (size_t)TKP + t0 +
                t8) = vv;
    }
    __syncthreads();
  }
}

// ---------------------------------------------------------------------------
// cls_fill: t=0 rows of Qh/Kh from the lin buffers' cls column (n = NSP).
// ---------------------------------------------------------------------------
__global__ __launch_bounds__(768) void cls_fill_kernel(
    const f16* __restrict__ qlin, const f16* __restrict__ klin,
    f16* __restrict__ Qh, f16* __restrict__ Kh) {
  const int b = blockIdx.x;
  const int c = threadIdx.x;
  Qh[(((size_t)(b * NHEADS + (c >> 6))) * TQP) * 64 + (c & 63)] =
      qlin[((size_t)b * CDIM + c) * NSPX + NSP];
  Kh[(((size_t)(b * NHEADS + (c >> 6))) * TKP) * 64 + (c & 63)] =
      klin[((size_t)b * CDIM + c) * NSPX + NSP];
}

// ---------------------------------------------------------------------------
// MFMA flash attention. Grid (7, 12, 8), 256 threads = 4 waves; wave tile
// 64 q x 64 keys (bq[4][2], sacc[4][4], oacc[4][4]).
// ---------------------------------------------------------------------------
__global__ __launch_bounds__(256) void attn_mfma_kernel(
    const f16* __restrict__ Qh, const f16* __restrict__ Kh,
    const f16* __restrict__ Vht, f16* __restrict__ o16) {
  __shared__ __align__(16) f16 Ks[64 * 72];   // [key][d], pad 8
  __shared__ __align__(16) f16 Vt[64 * 72];   // [d][key], pad 8
  const int qt = blockIdx.x, h = blockIdx.y, b = blockIdx.z;
  const int tid = threadIdx.x;
  const int lane = tid & 63;
  const int w = tid >> 6;
  const int l15 = lane & 15, l4 = lane >> 4;
  const int q0 = qt * 256 + w * 64;

  const f16* Qp = Qh + ((size_t)(b * NHEADS + h) * TQP) * 64;
  const f16* Kp = Kh + ((size_t)(b * NHEADS + h) * TKP) * 64;
  const f16* Vp = Vht + ((size_t)(b * NHEADS + h) * 64) * TKP;

  f16x8_t bq[4][2];
#pragma unroll
  for (int qi = 0; qi < 4; qi++)
#pragma unroll
    for (int kf = 0; kf < 2; kf++)
      bq[qi][kf] = *(const f16x8_t*)(Qp + (size_t)(q0 + qi * 16 + l15) * 64 +
                                     kf * 32 + l4 * 8);

  f32x4_t oacc[4][4];
#pragma unroll
  for (int df = 0; df < 4; df++)
#pragma unroll
    for (int qi = 0; qi < 4; qi++) oacc[df][qi] = (f32x4_t){0.f, 0.f, 0.f, 0.f};
  float mrow[4] = {-1e30f, -1e30f, -1e30f, -1e30f};
  float lrow[4] = {0.f, 0.f, 0.f, 0.f};

  const int sr = tid >> 2, sc = (tid & 3) * 16;

  for (int kv0 = 0; kv0 < TKP; kv0 += 64) {
    const f16* kg = Kp + (size_t)(kv0 + sr) * 64 + sc;
    uint4 kl0 = *(const uint4*)kg;
    uint4 kl1 = *(const uint4*)(kg + 8);
    const f16* vg = Vp + (size_t)sr * TKP + kv0 + sc;
    uint4 vl0 = *(const uint4*)vg;
    uint4 vl1 = *(const uint4*)(vg + 8);
    __syncthreads();
    *(uint4*)(Ks + sr * 72 + sc) = kl0;
    *(uint4*)(Ks + sr * 72 + sc + 8) = kl1;
    *(uint4*)(Vt + sr * 72 + sc) = vl0;
    *(uint4*)(Vt + sr * 72 + sc + 8) = vl1;
    __syncthreads();

    // ---- S^T = K * Q^T ----
    f32x4_t sacc[4][4];
#pragma unroll
    for (int ki = 0; ki < 4; ki++)
#pragma unroll
      for (int qi = 0; qi < 4; qi++)
        sacc[ki][qi] = (f32x4_t){0.f, 0.f, 0.f, 0.f};
#pragma unroll
    for (int kf = 0; kf < 2; kf++) {
#pragma unroll
      for (int ki = 0; ki < 4; ki++) {
        f16x8_t ak =
            *(const f16x8_t*)(Ks + (ki * 16 + l15) * 72 + kf * 32 + l4 * 8);
#pragma unroll
        for (int qi = 0; qi < 4; qi++)
          sacc[ki][qi] = __builtin_amdgcn_mfma_f32_16x16x32_f16(
              ak, bq[qi][kf], sacc[ki][qi], 0, 0, 0);
      }
    }

    // ---- scale + mask + online softmax ----
    float pmax[4] = {-1e30f, -1e30f, -1e30f, -1e30f};
#pragma unroll
    for (int ki = 0; ki < 4; ki++) {
      const int keyb = kv0 + ki * 16 + l4 * 4;
#pragma unroll
      for (int qi = 0; qi < 4; qi++) {
#pragma unroll
        for (int rr = 0; rr < 4; rr++) {
          float s = sacc[ki][qi][rr] * ATTN_SCALE;
          if (keyb + rr >= NKTOK) s = -1e30f;
          sacc[ki][qi][rr] = s;
          pmax[qi] = fmaxf(pmax[qi], s);
        }
      }
    }
#pragma unroll
    for (int qi = 0; qi < 4; qi++) {
      pmax[qi] = fmaxf(pmax[qi], __shfl_xor(pmax[qi], 16, 64));
      pmax[qi] = fmaxf(pmax[qi], __shfl_xor(pmax[qi], 32, 64));
      float mnew = fmaxf(mrow[qi], pmax[qi]);
      float alpha = __expf(mrow[qi] - mnew);
      mrow[qi] = mnew;
      lrow[qi] *= alpha;
#pragma unroll
      for (int df = 0; df < 4; df++) {
        oacc[df][qi][0] *= alpha;
        oacc[df][qi][1] *= alpha;
        oacc[df][qi][2] *= alpha;
        oacc[df][qi][3] *= alpha;
      }
    }

    // ---- per-ki P + PV ----
#pragma unroll
    for (int ki = 0; ki < 4; ki++) {
      f16x4_t pb[4];
#pragma unroll
      for (int qi = 0; qi < 4; qi++) {
        float p0 = __expf(sacc[ki][qi][0] - mrow[qi]);
        float p1 = __expf(sacc[ki][qi][1] - mrow[qi]);
        float p2 = __expf(sacc[ki][qi][2] - mrow[qi]);
        float p3 = __expf(sacc[ki][qi][3] - mrow[qi]);
        lrow[qi] += p0 + p1 + p2 + p3;
        f16x4_t pv = {(f16)p0, (f16)p1, (f16)p2, (f16)p3};
        pb[qi] = pv;
      }
#pragma unroll
      for (int df = 0; df < 4; df++) {
        f16x4_t av =
            *(const f16x4_t*)(Vt + (df * 16 + l15) * 72 + ki * 16 + l4 * 4);
#pragma unroll
        for (int qi = 0; qi < 4; qi++)
          oacc[df][qi] = __builtin_amdgcn_mfma_f32_16x16x16f16(
              av, pb[qi], oacc[df][qi], 0, 0, 0);
      }
    }
  }

  float inv[4];
#pragma unroll
  for (int qi = 0; qi < 4; qi++) {
    float l = lrow[qi];
    l += __shfl_xor(l, 16, 64);
    l += __shfl_xor(l, 32, 64);
    inv[qi] = 1.f / l;
  }
#pragma unroll
  for (int qi = 0; qi < 4; qi++) {
    const int q = q0 + qi * 16 + l15;
    if (q < NQTOK) {
      f16* op = o16 + ((size_t)(b * NQTOK + q)) * CDIM + h * 64 + l4 * 4;
#pragma unroll
      for (int df = 0; df < 4; df++) {
        f16x4_t ov = {(f16)(oacc[df][qi][0] * inv[qi]),
                      (f16)(oacc[df][qi][1] * inv[qi]),
                      (f16)(oacc[df][qi][2] * inv[qi]),
                      (f16)(oacc[df][qi][3] * inv[qi])};
        *(f16x4_t*)(op + df * 16) = ov;
      }
    }
  }
}

// ---------------------------------------------------------------------------
extern "C" void kernel_launch(void* const* d_in, const int* in_sizes, int n_in,
                              void* d_out, int out_size, void* d_ws, size_t ws_size,
                              hipStream_t stream) {
  const float* x      = (const float*)d_in[0];
  const float* cls    = (const float*)d_in[1];
  const float* Wq     = (const float*)d_in[2];
  const float* bq     = (const float*)d_in[3];
  const float* Wk     = (const float*)d_in[4];
  const float* bk     = (const float*)d_in[5];
  const float* Wv     = (const float*)d_in[6];
  const float* bv     = (const float*)d_in[7];
  const float* conv_q = (const float*)d_in[8];
  const float* conv_k = (const float*)d_in[9];
  const float* conv_v = (const float*)d_in[10];
  const float* lnq_w  = (const float*)d_in[11];
  const float* lnq_b  = (const float*)d_in[12];
  const float* lnk_w  = (const float*)d_in[13];
  const float* lnk_b  = (const float*)d_in[14];
  const float* lnv_w  = (const float*)d_in[15];
  const float* lnv_b  = (const float*)d_in[16];
  const float* Wproj  = (const float*)d_in[17];
  const float* bproj  = (const float*)d_in[18];

  // Workspace layout (bytes). Total = 124,747,776 B ≈ 124.7 MB.
  char* wsb = (char*)d_ws;
  f16*   Xt     = (f16*)(wsb + 0);           // 8*1792*768*2 = 22,020,096
  f16*   W16    = (f16*)(wsb + 22020096);    //  4,718,592
  f16*   q_lin  = (f16*)(wsb + 26738688);    // 8*768*1576*2 = 19,365,888
  f16*   k_lin  = (f16*)(wsb + 46104576);    // 19,365,888
  f16*   v_lin  = (f16*)(wsb + 65470464);    // 19,365,888
  f16*   k_pool = (f16*)(wsb + 84836352);    //  4,816,896
  f16*   v_pool = (f16*)(wsb + 89653248);    //  4,816,896
  f16*   Kh     = (f16*)(wsb + 94470144);    //  5,505,024
  f16*   Vht    = (f16*)(wsb + 99975168);    //  5,505,024
  f16*   q_pool = (f16*)(wsb + 105480192);   // 19,267,584 -> end 124,747,776
  f16*   Qh     = Xt;      // alias: Xt dead after QKV GEMM (sizes equal)
  f16*   o16    = v_lin;   // alias: v_lin (+294KB of dead k_pool) at proj;
                           // attn writes only rows < 12552

  f16* W16p = W16 + (size_t)3 * WELEM;

  // 1. convert weights to fp16
  convert4_kernel<<<dim3(576, 4), 256, 0, stream>>>(Wq, Wk, Wv, Wproj, W16);

  // 2. transpose+convert X (+cls as row 1568) -> Xt
  transpose_x_kernel<<<dim3(56, 24, BATCH), 256, 0, stream>>>(x, cls, Xt);

  // 3. fused QKV MFMA GEMM (A-from-global, B via gld_lds) -> f16 lin buffers
  gemm_qkv_f16_kernel<<<1008, 256, 0, stream>>>(W16, Xt, bq, bk, bv, q_lin);

  // 4. cls rows of Qh/Kh
  cls_fill_kernel<<<BATCH, 768, 0, stream>>>(q_lin, k_lin, Qh, Kh);

  // 5. depthwise convs (q stride-1; k/v stride-2, 4 ch/block)
  dwconv_q_kernel<<<BATCH * CDIM, 256, 0, stream>>>(q_lin, conv_q, q_pool);
  dwconv_kv_kernel<<<dim3(BATCH * CDIM / 4, 2), 256, 0, stream>>>(
      k_lin, v_lin, conv_k, conv_v, k_pool, v_pool);

  // 6. fused LN + pack (q and k in one launch; v separate)
  ln_pack_qk2_kernel<<<dim3(62, BATCH), 256, 0, stream>>>(
      q_pool, k_pool, lnq_w, lnq_b, lnk_w, lnk_b, Qh, Kh);
  ln_pack_v_kernel<<<dim3(14, BATCH), 256, 0, stream>>>(v_pool, v_lin, lnv_w,
                                                        lnv_b, Vht);

  // 7. MFMA attention (64-q wave tiles) -> o16
  attn_mfma_kernel<<<dim3(7, NHEADS, BATCH), 256, 0, stream>>>(Qh, Kh, Vht,
                                                               o16);

  // 8. projection MFMA GEMM -> d_out
  float* xo = (float*)d_out;
  float* cls_o = (float*)d_out + (size_t)BATCH * CDIM * NSP;
  gemm_proj_f16_kernel<<<300, 256, 0, stream>>>(W16p, o16, bproj, xo, cls_o);
}

// Round 14
// 336.102 us; speedup vs baseline: 1.0623x; 1.0623x over previous
//
#include <hip/hip_runtime.h>

#define CDIM 768
#define BATCH 8
#define LDEPTH 8
#define HHEIGHT 14
#define WWIDTH 14
#define NSP 1568      // 8*14*14 spatial tokens (input / q)
#define NSPX 1576     // lin-buffer row stride: NSP + cls col (1568) + pad
#define NQTOK 1569    // +cls
#define NKSP 392      // 8*7*7 spatial tokens (k/v after pool)
#define NKTOK 393
#define NHEADS 12
#define HEADDIM 64
#define ATTN_SCALE 0.125f
#define LN_EPS 1e-6f
#define MTOK (BATCH * NQTOK)   // 12552 tokens for proj GEMM
#define NPAD_X 1792            // Xt padded rows per batch (7 tiles * 256)
#define WELEM (CDIM * CDIM)    // 589824
#define TQP 1792               // padded q tokens per (b,h)  (7*256)
#define TKP 448                // padded kv tokens per (b,h) (7*64)

typedef _Float16 f16;
typedef _Float16 f16x8_t __attribute__((ext_vector_type(8)));
typedef _Float16 f16x4_t __attribute__((ext_vector_type(4)));
typedef float f32x4_t __attribute__((ext_vector_type(4)));
typedef float f32x2_t __attribute__((ext_vector_type(2)));

// global -> LDS direct 16B copy (wave-uniform LDS base + lane*16)
__device__ __forceinline__ void gld_lds16(const void* g, void* l) {
  __builtin_amdgcn_global_load_lds(
      (const __attribute__((address_space(1))) void*)g,
      (__attribute__((address_space(3))) void*)l, 16, 0, 0);
}

// ---------------------------------------------------------------------------
// fp32 -> fp16 convert for the 4 weight matrices (one launch, grid.y = mat)
// ---------------------------------------------------------------------------
__global__ __launch_bounds__(256) void convert4_kernel(
    const float* __restrict__ s0, const float* __restrict__ s1,
    const float* __restrict__ s2, const float* __restrict__ s3,
    f16* __restrict__ dst) {
  const int mat = blockIdx.y;
  const float* src = (mat == 0) ? s0 : (mat == 1) ? s1 : (mat == 2) ? s2 : s3;
  int i = (blockIdx.x * 256 + threadIdx.x) * 4;
  if (i < WELEM) {
    float4 v = *(const float4*)&src[i];
    f16x4_t h = {(f16)v.x, (f16)v.y, (f16)v.z, (f16)v.w};
    *(f16x4_t*)&dst[(size_t)mat * WELEM + i] = h;
  }
}

// ---------------------------------------------------------------------------
// Transpose+convert X: (B,768,1568) f32 -> Xt (B,1792,768) f16.
// Row 1568 = class_token; rows >1568 = 0.
// ---------------------------------------------------------------------------
__global__ __launch_bounds__(256) void transpose_x_kernel(
    const float* __restrict__ X, const float* __restrict__ cls,
    f16* __restrict__ Xt) {
  __shared__ float t[32][33];
  const int b = blockIdx.z;
  const int k0 = blockIdx.y * 32;
  const int n0 = blockIdx.x * 32;   // grid.x = 56 (1792/32)
  const int tx = threadIdx.x & 31, ty = threadIdx.x >> 5;
#pragma unroll
  for (int i = 0; i < 4; i++) {
    int k = k0 + ty + i * 8;
    int n = n0 + tx;
    float v;
    if (n < NSP)
      v = X[((size_t)b * CDIM + k) * NSP + n];
    else if (n == NSP)
      v = cls[b * CDIM + k];
    else
      v = 0.f;
    t[ty + i * 8][tx] = v;
  }
  __syncthreads();
#pragma unroll
  for (int i = 0; i < 4; i++) {
    int n = n0 + ty + i * 8;
    Xt[((size_t)b * NPAD_X + n) * CDIM + k0 + tx] = (f16)t[tx][ty + i * 8];
  }
}

// ---------------------------------------------------------------------------
// Fused QKV MFMA GEMM. Block tile 128(m) x 256(n), BK=32, 4 waves, wave tile
// 64x128 (acc[4][8]). global_load_lds staging with SOURCE-side XOR swizzle
// matched by read-side XOR (round-12 verified structure). 3 blocks/CU.
// 1D grid 1008, XCD swizzle: batch = bid&7.
// ---------------------------------------------------------------------------
__global__ __launch_bounds__(256, 3) void gemm_qkv_f16_kernel(
    const f16* __restrict__ W16, const f16* __restrict__ Xt,
    const float* __restrict__ bq, const float* __restrict__ bk,
    const float* __restrict__ bv, f16* __restrict__ OutBase) {
  __shared__ __align__(16) f16 Asm[128 * 32];   // 8 KB
  __shared__ __align__(16) f16 Bsm[256 * 32];   // 16 KB

  const int bid = blockIdx.x;
  const int b = bid & 7;
  const int rem = bid >> 3;
  const int mat = rem / 42;
  const int rem2 = rem % 42;
  const int m0 = (rem2 / 7) * 128;
  const int n0 = (rem2 % 7) * 256;
  const int tid = threadIdx.x;
  const int lane = tid & 63;
  const int w = tid >> 6;
  const int wr = w >> 1, wc = w & 1;
  const int l15 = lane & 15, l4 = lane >> 4;

  const f16* A16 = W16 + (size_t)mat * WELEM;
  const float* bias = (mat == 0) ? bq : (mat == 1) ? bk : bv;
  f16* Out = OutBase + (size_t)mat * ((size_t)BATCH * CDIM * NSPX);

  const int srow = lane >> 2;
  const int skq = ((lane & 3) ^ ((lane >> 3) & 3)) * 8;
  const f16* Ag = A16 + (size_t)(m0 + w * 32 + srow) * CDIM + skq;
  const f16* Bg = Xt + ((size_t)b * NPAD_X + n0 + w * 64 + srow) * CDIM + skq;
  f16* lA = Asm + w * 32 * 32;
  f16* lB = Bsm + w * 64 * 32;

  const int rsw = (l15 >> 1) & 3;
  const int kchunk = (l4 ^ rsw) * 8;

  f32x4_t acc[4][8];
#pragma unroll
  for (int i = 0; i < 4; i++)
#pragma unroll
    for (int j = 0; j < 8; j++) acc[i][j] = (f32x4_t){0.f, 0.f, 0.f, 0.f};

  for (int k0 = 0; k0 < CDIM; k0 += 32) {
    gld_lds16(Ag + k0, lA);
    gld_lds16(Ag + 16 * CDIM + k0, lA + 16 * 32);
    gld_lds16(Bg + k0, lB);
    gld_lds16(Bg + 16 * CDIM + k0, lB + 16 * 32);
    gld_lds16(Bg + 32 * CDIM + k0, lB + 32 * 32);
    gld_lds16(Bg + 48 * CDIM + k0, lB + 48 * 32);
    __syncthreads();
    f16x8_t af[4];
#pragma unroll
    for (int mi = 0; mi < 4; mi++)
      af[mi] = *(const f16x8_t*)(Asm + (wr * 64 + mi * 16 + l15) * 32 + kchunk);
#pragma unroll
    for (int ni = 0; ni < 8; ni++) {
      f16x8_t bfv =
          *(const f16x8_t*)(Bsm + (wc * 128 + ni * 16 + l15) * 32 + kchunk);
#pragma unroll
      for (int mi = 0; mi < 4; mi++)
        acc[mi][ni] = __builtin_amdgcn_mfma_f32_16x16x32_f16(
            af[mi], bfv, acc[mi][ni], 0, 0, 0);
    }
    __syncthreads();
  }

#pragma unroll
  for (int mi = 0; mi < 4; mi++) {
    const int mbase = m0 + wr * 64 + mi * 16 + l4 * 4;
#pragma unroll
    for (int ni = 0; ni < 8; ni++) {
      const int n = n0 + wc * 128 + ni * 16 + l15;
      if (n < NQTOK) {   // n == 1568 is the cls column
#pragma unroll
        for (int r = 0; r < 4; r++) {
          Out[((size_t)b * CDIM + mbase + r) * NSPX + n] =
              (f16)(acc[mi][ni][r] + bias[mbase + r]);
        }
      }
    }
  }
}

// ---------------------------------------------------------------------------
// Projection MFMA GEMM, same 128x256 structure, 3 blocks/CU. 1D grid 300,
// bijective XCD swizzle (nwg=300: q=37, r=4).
// ---------------------------------------------------------------------------
__global__ __launch_bounds__(256, 3) void gemm_proj_f16_kernel(
    const f16* __restrict__ Wp16, const f16* __restrict__ o16,
    const float* __restrict__ bias, float* __restrict__ xo,
    float* __restrict__ cls_o) {
  __shared__ __align__(16) f16 Asm[128 * 32];
  __shared__ __align__(16) f16 Bsm[256 * 32];

  const int bid = blockIdx.x;
  const int xcd = bid & 7, pos_ = bid >> 3;
  const int base = (xcd < 4) ? xcd * 38 : 152 + (xcd - 4) * 37;
  const int wgid = base + pos_;
  const int m0 = (wgid / 50) * 128;
  const int n0 = (wgid % 50) * 256;
  const int tid = threadIdx.x;
  const int lane = tid & 63;
  const int w = tid >> 6;
  const int wr = w >> 1, wc = w & 1;
  const int l15 = lane & 15, l4 = lane >> 4;

  const int srow = lane >> 2;
  const int skq = ((lane & 3) ^ ((lane >> 3) & 3)) * 8;
  const f16* Ag = Wp16 + (size_t)(m0 + w * 32 + srow) * CDIM + skq;
  const f16* Bg = o16 + (size_t)(n0 + w * 64 + srow) * CDIM + skq;
  f16* lA = Asm + w * 32 * 32;
  f16* lB = Bsm + w * 64 * 32;

  const int rsw = (l15 >> 1) & 3;
  const int kchunk = (l4 ^ rsw) * 8;

  f32x4_t acc[4][8];
#pragma unroll
  for (int i = 0; i < 4; i++)
#pragma unroll
    for (int j = 0; j < 8; j++) acc[i][j] = (f32x4_t){0.f, 0.f, 0.f, 0.f};

  for (int k0 = 0; k0 < CDIM; k0 += 32) {
    gld_lds16(Ag + k0, lA);
    gld_lds16(Ag + 16 * CDIM + k0, lA + 16 * 32);
    gld_lds16(Bg + k0, lB);
    gld_lds16(Bg + 16 * CDIM + k0, lB + 16 * 32);
    gld_lds16(Bg + 32 * CDIM + k0, lB + 32 * 32);
    gld_lds16(Bg + 48 * CDIM + k0, lB + 48 * 32);
    __syncthreads();
    f16x8_t af[4];
#pragma unroll
    for (int mi = 0; mi < 4; mi++)
      af[mi] = *(const f16x8_t*)(Asm + (wr * 64 + mi * 16 + l15) * 32 + kchunk);
#pragma unroll
    for (int ni = 0; ni < 8; ni++) {
      f16x8_t bfv =
          *(const f16x8_t*)(Bsm + (wc * 128 + ni * 16 + l15) * 32 + kchunk);
#pragma unroll
      for (int mi = 0; mi < 4; mi++)
        acc[mi][ni] = __builtin_amdgcn_mfma_f32_16x16x32_f16(
            af[mi], bfv, acc[mi][ni], 0, 0, 0);
    }
    __syncthreads();
  }

#pragma unroll
  for (int ni = 0; ni < 8; ni++) {
    const int tok = n0 + wc * 128 + ni * 16 + l15;
    if (tok < MTOK) {
      const int bb = tok / NQTOK;
      const int nn = tok % NQTOK;
#pragma unroll
      for (int mi = 0; mi < 4; mi++) {
        const int mbase = m0 + wr * 64 + mi * 16 + l4 * 4;
#pragma unroll
        for (int r = 0; r < 4; r++) {
          float v = acc[mi][ni][r] + bias[mbase + r];
          if (nn == 0)
            cls_o[bb * CDIM + mbase + r] = v;
          else
            xo[((size_t)bb * CDIM + mbase + r) * (size_t)NSP + nn - 1] = v;
        }
      }
    }
  }
}

// ---------------------------------------------------------------------------
// Depthwise conv for q (stride 1, out 8x14x14). One block per (b,c) plane.
// L-fastest padded LDS volume (round-12 verified).
// ---------------------------------------------------------------------------
__global__ __launch_bounds__(256) void dwconv_q_kernel(
    const f16* __restrict__ q_lin, const float* __restrict__ cq,
    f16* __restrict__ q_pool) {
  __shared__ float vol[16 * 196];   // 12,544 B
  __shared__ float wsm[27];
  const int c = blockIdx.x % CDIM;
  const int b = blockIdx.x / CDIM;
  const f16* xb = q_lin + ((size_t)b * CDIM + c) * (size_t)NSPX;

  for (int i = threadIdx.x; i < 16 * 196; i += 256) vol[i] = 0.f;
  if (threadIdx.x < 27) wsm[threadIdx.x] = cq[c * 27 + threadIdx.x];
  __syncthreads();
  for (int i = threadIdx.x; i < NSP; i += 256) {
    int li = i / 196;
    int r = i - li * 196;
    int hi = r / 14;
    int wi = r - hi * 14;
    vol[(wi + 1) * 196 + (hi + 1) * 12 + (li + 1)] = (float)xb[i];
  }
  __syncthreads();

  if (threadIdx.x < 196) {
    const int ho = threadIdx.x / 14;
    const int wo = threadIdx.x - ho * 14;
    float sums[8];
#pragma unroll
    for (int lo = 0; lo < 8; lo++) sums[lo] = 0.f;
#pragma unroll
    for (int kh = 0; kh < 3; kh++) {
#pragma unroll
      for (int kw = 0; kw < 3; kw++) {
        const float* p = &vol[(wo + kw) * 196 + (ho + kh) * 12];
        float z[10];
        *(f32x4_t*)&z[0] = *(const f32x4_t*)p;
        *(f32x4_t*)&z[4] = *(const f32x4_t*)(p + 4);
        *(f32x2_t*)&z[8] = *(const f32x2_t*)(p + 8);
        const float w0 = wsm[0 + kh * 3 + kw];
        const float w1 = wsm[9 + kh * 3 + kw];
        const float w2 = wsm[18 + kh * 3 + kw];
#pragma unroll
        for (int lo = 0; lo < 8; lo++) {
          sums[lo] = fmaf(z[lo], w0, sums[lo]);
          sums[lo] = fmaf(z[lo + 1], w1, sums[lo]);
          sums[lo] = fmaf(z[lo + 2], w2, sums[lo]);
        }
      }
    }
    f16* ob = q_pool + ((size_t)b * CDIM + c) * (size_t)NSP;
    const int hw = ho * 14 + wo;
#pragma unroll
    for (int lo = 0; lo < 8; lo++) ob[lo * 196 + hw] = (f16)sums[lo];
  }
}

// ---------------------------------------------------------------------------
// Depthwise conv for k/v (stride 2, out 8x7x7). 4 channels per block.
// ---------------------------------------------------------------------------
__global__ __launch_bounds__(256) void dwconv_kv_kernel(
    const f16* __restrict__ k_lin, const f16* __restrict__ v_lin,
    const float* __restrict__ ck, const float* __restrict__ cv,
    f16* __restrict__ k_pool, f16* __restrict__ v_pool) {
  __shared__ float vol4[4][16 * 196];   // 50,176 B
  __shared__ float wsm4[4][27];
  const int which = blockIdx.y;
  const f16* X = which ? v_lin : k_lin;
  const float* wconv = which ? cv : ck;
  f16* Out = which ? v_pool : k_pool;
  const int cg = blockIdx.x % (CDIM / 4);
  const int b = blockIdx.x / (CDIM / 4);
  const int c0 = cg * 4;
  const f16* xb0 = X + ((size_t)b * CDIM + c0) * (size_t)NSPX;

  for (int i = threadIdx.x; i < 4 * 16 * 196; i += 256)
    ((float*)vol4)[i] = 0.f;
  if (threadIdx.x < 108) {
    int ch = threadIdx.x / 27;
    int j = threadIdx.x - ch * 27;
    wsm4[ch][j] = wconv[(c0 + ch) * 27 + j];
  }
  __syncthreads();
  for (int i = threadIdx.x; i < 4 * NSP; i += 256) {
    int ch = i / NSP;
    int j = i - ch * NSP;
    int li = j / 196;
    int r = j - li * 196;
    int hi = r / 14;
    int wi = r - hi * 14;
    vol4[ch][(wi + 1) * 196 + (hi + 1) * 12 + (li + 1)] =
        (float)xb0[(size_t)ch * NSPX + j];
  }
  __syncthreads();

  if (threadIdx.x < 196) {
    const int ch = threadIdx.x / 49;
    const int p2 = threadIdx.x - ch * 49;
    const int ho = p2 / 7;
    const int wo = p2 - ho * 7;
    const float* vol = vol4[ch];
    const float* wsm = wsm4[ch];
    float sums[8];
#pragma unroll
    for (int lo = 0; lo < 8; lo++) sums[lo] = 0.f;
#pragma unroll
    for (int kh = 0; kh < 3; kh++) {
#pragma unroll
      for (int kw = 0; kw < 3; kw++) {
        const float* p = &vol[(wo * 2 + kw) * 196 + (ho * 2 + kh) * 12];
        float z[10];
        *(f32x4_t*)&z[0] = *(const f32x4_t*)p;
        *(f32x4_t*)&z[4] = *(const f32x4_t*)(p + 4);
        *(f32x2_t*)&z[8] = *(const f32x2_t*)(p + 8);
        const float w0 = wsm[0 + kh * 3 + kw];
        const float w1 = wsm[9 + kh * 3 + kw];
        const float w2 = wsm[18 + kh * 3 + kw];
#pragma unroll
        for (int lo = 0; lo < 8; lo++) {
          sums[lo] = fmaf(z[lo], w0, sums[lo]);
          sums[lo] = fmaf(z[lo + 1], w1, sums[lo]);
          sums[lo] = fmaf(z[lo + 2], w2, sums[lo]);
        }
      }
    }
    f16* ob = Out + ((size_t)b * CDIM + c0 + ch) * (size_t)NKSP;
    const int hw = ho * 7 + wo;
#pragma unroll
    for (int lo = 0; lo < 8; lo++) ob[lo * 49 + hw] = (f16)sums[lo];
  }
}

// ---------------------------------------------------------------------------
// Fused LayerNorm + head-pack for q AND k in one launch: grid (62, B).
// ---------------------------------------------------------------------------
__global__ __launch_bounds__(256) void ln_pack_qk2_kernel(
    const f16* __restrict__ qp, const f16* __restrict__ kp,
    const float* __restrict__ lnq_w, const float* __restrict__ lnq_b,
    const float* __restrict__ lnk_w, const float* __restrict__ lnk_b,
    f16* __restrict__ Qh, f16* __restrict__ Kh) {
  const int bx = blockIdx.x;
  const bool isq = bx < 49;
  const f16* xp = isq ? qp : kp;
  const float* ln_w = isq ? lnq_w : lnk_w;
  const float* ln_b = isq ? lnq_b : lnk_b;
  f16* OutH = isq ? Qh : Kh;
  const int np = isq ? NSP : NKSP;
  const int tp = isq ? TQP : TKP;
  const int b = blockIdx.y;
  const int p0 = (isq ? bx : bx - 49) * 32;
  const int tid = threadIdx.x;
  const int pl = tid & 31;
  const int grp = tid >> 5;
  const int pos = p0 + pl;
  const bool act = pos < np;
  const f16* Xb = xp + (size_t)b * CDIM * (size_t)np;

  __shared__ __align__(16) f16 tile[32][784];
  __shared__ float r1[8][33], r2[8][33];
  __shared__ float smean[32], srstd[32];

  const int swz = (pl & 7) << 3;
  float s1 = 0.f, s2 = 0.f;
  for (int cc = 0; cc < 12; cc++) {
    const int c0 = grp * 96 + cc * 8;
    f16x8_t hv;
#pragma unroll
    for (int i = 0; i < 8; i++) {
      f16 h = act ? Xb[(size_t)(c0 + i) * np + pos] : (f16)0.f;
      hv[i] = h;
      float v = (float)h;
      s1 += v;
      s2 = fmaf(v, v, s2);
    }
    *(f16x8_t*)&tile[pl][c0 ^ swz] = hv;
  }
  r1[grp][pl] = s1;
  r2[grp][pl] = s2;
  __syncthreads();
  if (tid < 32) {
    float t1 = 0.f, t2 = 0.f;
#pragma unroll
    for (int g = 0; g < 8; g++) { t1 += r1[g][tid]; t2 += r2[g][tid]; }
    float mean = t1 * (1.f / 768.f);
    float var = t2 * (1.f / 768.f) - mean * mean;
    smean[tid] = mean;
    srstd[tid] = rsqrtf(var + LN_EPS);
  }
  __syncthreads();

  const int tl = tid >> 3, d8 = (tid & 7) * 8;
  const float mean = smean[tl], rstd = srstd[tl];
  const bool wv = (p0 + tl) < np;
  const int tswz = (tl & 7) << 3;
#pragma unroll
  for (int h = 0; h < NHEADS; h++) {
    const int c = h * 64 + d8;
    f16x8_t raw = *(const f16x8_t*)&tile[tl][c ^ tswz];
    float4 w1 = *(const float4*)&ln_w[c];
    float4 w2 = *(const float4*)&ln_w[c + 4];
    float4 b1 = *(const float4*)&ln_b[c];
    float4 b2 = *(const float4*)&ln_b[c + 4];
    f16x8_t ov;
    ov[0] = (f16)(((float)raw[0] - mean) * rstd * w1.x + b1.x);
    ov[1] = (f16)(((float)raw[1] - mean) * rstd * w1.y + b1.y);
    ov[2] = (f16)(((float)raw[2] - mean) * rstd * w1.z + b1.z);
    ov[3] = (f16)(((float)raw[3] - mean) * rstd * w1.w + b1.w);
    ov[4] = (f16)(((float)raw[4] - mean) * rstd * w2.x + b2.x);
    ov[5] = (f16)(((float)raw[5] - mean) * rstd * w2.y + b2.y);
    ov[6] = (f16)(((float)raw[6] - mean) * rstd * w2.z + b2.z);
    ov[7] = (f16)(((float)raw[7] - mean) * rstd * w2.w + b2.w);
    if (wv)
      *(uint4*)(OutH +
                (((size_t)(b * NHEADS + h)) * (size_t)tp + (p0 + tl + 1)) * 64 +
                d8) = *(uint4*)&ov;
  }
}

// ---------------------------------------------------------------------------
// Fused LayerNorm + transpose-pack for v. cls (t=0) raw from v_lin col NSP.
// ---------------------------------------------------------------------------
__global__ __launch_bounds__(256) void ln_pack_v_kernel(
    const f16* __restrict__ vp, const f16* __restrict__ vlin,
    const float* __restrict__ ln_w, const float* __restrict__ ln_b,
    f16* __restrict__ Vht) {
  const int b = blockIdx.y;
  const int t0 = blockIdx.x * 32;
  const int tid = threadIdx.x;
  const int pl = tid & 31;
  const int grp = tid >> 5;
  const int t = t0 + pl;
  const int pos = t - 1;
  const bool isv = (t >= 1) && (t < NKTOK);
  const f16* Vb = vp + (size_t)b * CDIM * (size_t)NKSP;

  __shared__ float r1[8][33], r2[8][33];
  __shared__ float smean[32], srstd[32];
  __shared__ __align__(16) f16 vtile[128][40];

  float s1 = 0.f, s2 = 0.f;
  if (isv) {
    for (int c = grp; c < CDIM; c += 8) {
      float v = (float)Vb[(size_t)c * NKSP + pos];
      s1 += v;
      s2 = fmaf(v, v, s2);
    }
  }
  r1[grp][pl] = s1;
  r2[grp][pl] = s2;
  __syncthreads();
  if (tid < 32) {
    float t1 = 0.f, t2 = 0.f;
#pragma unroll
    for (int g = 0; g < 8; g++) { t1 += r1[g][tid]; t2 += r2[g][tid]; }
    float mean = t1 * (1.f / 768.f);
    float var = t2 * (1.f / 768.f) - mean * mean;
    smean[tid] = mean;
    srstd[tid] = rsqrtf(var + LN_EPS);
  }
  __syncthreads();
  const float mean = smean[pl], rstd = srstd[pl];

  for (int cc = 0; cc < 6; cc++) {
#pragma unroll
    for (int i = 0; i < 16; i++) {
      int cl = grp * 16 + i;
      int c = cc * 128 + cl;
      float outv;
      if (isv)
        outv = ((float)Vb[(size_t)c * NKSP + pos] - mean) * rstd * ln_w[c] +
               ln_b[c];
      else if (t == 0)
        outv = (float)vlin[((size_t)b * CDIM + c) * NSPX + NSP];
      else
        outv = 0.f;
      vtile[cl][pl] = (f16)outv;
    }
    __syncthreads();
#pragma unroll
    for (int it = 0; it < 2; it++) {
      int idx = it * 256 + tid;
      int cl = idx >> 2, t8 = (idx & 3) * 8;
      uint4 vv = *(const uint4*)&vtile[cl][t8];
      *(uint4*)(Vht + ((size_t)b * CDIM + cc * 128 + cl) * (size_t)TKP + t0 +
                t8) = vv;
    }
    __syncthreads();
  }
}

// ---------------------------------------------------------------------------
// cls_fill: t=0 rows of Qh/Kh from the lin buffers' cls column (n = NSP).
// ---------------------------------------------------------------------------
__global__ __launch_bounds__(768) void cls_fill_kernel(
    const f16* __restrict__ qlin, const f16* __restrict__ klin,
    f16* __restrict__ Qh, f16* __restrict__ Kh) {
  const int b = blockIdx.x;
  const int c = threadIdx.x;
  Qh[(((size_t)(b * NHEADS + (c >> 6))) * TQP) * 64 + (c & 63)] =
      qlin[((size_t)b * CDIM + c) * NSPX + NSP];
  Kh[(((size_t)(b * NHEADS + (c >> 6))) * TKP) * 64 + (c & 63)] =
      klin[((size_t)b * CDIM + c) * NSPX + NSP];
}

// ---------------------------------------------------------------------------
// MFMA flash attention. Grid (7, 12, 8), 256 threads = 4 waves; wave tile
// 64 q x 64 keys (bq[4][2], sacc[4][4], oacc[4][4]).
// ---------------------------------------------------------------------------
__global__ __launch_bounds__(256) void attn_mfma_kernel(
    const f16* __restrict__ Qh, const f16* __restrict__ Kh,
    const f16* __restrict__ Vht, f16* __restrict__ o16) {
  __shared__ __align__(16) f16 Ks[64 * 72];   // [key][d], pad 8
  __shared__ __align__(16) f16 Vt[64 * 72];   // [d][key], pad 8
  const int qt = blockIdx.x, h = blockIdx.y, b = blockIdx.z;
  const int tid = threadIdx.x;
  const int lane = tid & 63;
  const int w = tid >> 6;
  const int l15 = lane & 15, l4 = lane >> 4;
  const int q0 = qt * 256 + w * 64;

  const f16* Qp = Qh + ((size_t)(b * NHEADS + h) * TQP) * 64;
  const f16* Kp = Kh + ((size_t)(b * NHEADS + h) * TKP) * 64;
  const f16* Vp = Vht + ((size_t)(b * NHEADS + h) * 64) * TKP;

  f16x8_t bq[4][2];
#pragma unroll
  for (int qi = 0; qi < 4; qi++)
#pragma unroll
    for (int kf = 0; kf < 2; kf++)
      bq[qi][kf] = *(const f16x8_t*)(Qp + (size_t)(q0 + qi * 16 + l15) * 64 +
                                     kf * 32 + l4 * 8);

  f32x4_t oacc[4][4];
#pragma unroll
  for (int df = 0; df < 4; df++)
#pragma unroll
    for (int qi = 0; qi < 4; qi++) oacc[df][qi] = (f32x4_t){0.f, 0.f, 0.f, 0.f};
  float mrow[4] = {-1e30f, -1e30f, -1e30f, -1e30f};
  float lrow[4] = {0.f, 0.f, 0.f, 0.f};

  const int sr = tid >> 2, sc = (tid & 3) * 16;

  for (int kv0 = 0; kv0 < TKP; kv0 += 64) {
    const f16* kg = Kp + (size_t)(kv0 + sr) * 64 + sc;
    uint4 kl0 = *(const uint4*)kg;
    uint4 kl1 = *(const uint4*)(kg + 8);
    const f16* vg = Vp + (size_t)sr * TKP + kv0 + sc;
    uint4 vl0 = *(const uint4*)vg;
    uint4 vl1 = *(const uint4*)(vg + 8);
    __syncthreads();
    *(uint4*)(Ks + sr * 72 + sc) = kl0;
    *(uint4*)(Ks + sr * 72 + sc + 8) = kl1;
    *(uint4*)(Vt + sr * 72 + sc) = vl0;
    *(uint4*)(Vt + sr * 72 + sc + 8) = vl1;
    __syncthreads();

    // ---- S^T = K * Q^T ----
    f32x4_t sacc[4][4];
#pragma unroll
    for (int ki = 0; ki < 4; ki++)
#pragma unroll
      for (int qi = 0; qi < 4; qi++)
        sacc[ki][qi] = (f32x4_t){0.f, 0.f, 0.f, 0.f};
#pragma unroll
    for (int kf = 0; kf < 2; kf++) {
#pragma unroll
      for (int ki = 0; ki < 4; ki++) {
        f16x8_t ak =
            *(const f16x8_t*)(Ks + (ki * 16 + l15) * 72 + kf * 32 + l4 * 8);
#pragma unroll
        for (int qi = 0; qi < 4; qi++)
          sacc[ki][qi] = __builtin_amdgcn_mfma_f32_16x16x32_f16(
              ak, bq[qi][kf], sacc[ki][qi], 0, 0, 0);
      }
    }

    // ---- scale + mask + online softmax ----
    float pmax[4] = {-1e30f, -1e30f, -1e30f, -1e30f};
#pragma unroll
    for (int ki = 0; ki < 4; ki++) {
      const int keyb = kv0 + ki * 16 + l4 * 4;
#pragma unroll
      for (int qi = 0; qi < 4; qi++) {
#pragma unroll
        for (int rr = 0; rr < 4; rr++) {
          float s = sacc[ki][qi][rr] * ATTN_SCALE;
          if (keyb + rr >= NKTOK) s = -1e30f;
          sacc[ki][qi][rr] = s;
          pmax[qi] = fmaxf(pmax[qi], s);
        }
      }
    }
#pragma unroll
    for (int qi = 0; qi < 4; qi++) {
      pmax[qi] = fmaxf(pmax[qi], __shfl_xor(pmax[qi], 16, 64));
      pmax[qi] = fmaxf(pmax[qi], __shfl_xor(pmax[qi], 32, 64));
      float mnew = fmaxf(mrow[qi], pmax[qi]);
      float alpha = __expf(mrow[qi] - mnew);
      mrow[qi] = mnew;
      lrow[qi] *= alpha;
#pragma unroll
      for (int df = 0; df < 4; df++) {
        oacc[df][qi][0] *= alpha;
        oacc[df][qi][1] *= alpha;
        oacc[df][qi][2] *= alpha;
        oacc[df][qi][3] *= alpha;
      }
    }

    // ---- per-ki P + PV ----
#pragma unroll
    for (int ki = 0; ki < 4; ki++) {
      f16x4_t pb[4];
#pragma unroll
      for (int qi = 0; qi < 4; qi++) {
        float p0 = __expf(sacc[ki][qi][0] - mrow[qi]);
        float p1 = __expf(sacc[ki][qi][1] - mrow[qi]);
        float p2 = __expf(sacc[ki][qi][2] - mrow[qi]);
        float p3 = __expf(sacc[ki][qi][3] - mrow[qi]);
        lrow[qi] += p0 + p1 + p2 + p3;
        f16x4_t pv = {(f16)p0, (f16)p1, (f16)p2, (f16)p3};
        pb[qi] = pv;
      }
#pragma unroll
      for (int df = 0; df < 4; df++) {
        f16x4_t av =
            *(const f16x4_t*)(Vt + (df * 16 + l15) * 72 + ki * 16 + l4 * 4);
#pragma unroll
        for (int qi = 0; qi < 4; qi++)
          oacc[df][qi] = __builtin_amdgcn_mfma_f32_16x16x16f16(
              av, pb[qi], oacc[df][qi], 0, 0, 0);
      }
    }
  }

  float inv[4];
#pragma unroll
  for (int qi = 0; qi < 4; qi++) {
    float l = lrow[qi];
    l += __shfl_xor(l, 16, 64);
    l += __shfl_xor(l, 32, 64);
    inv[qi] = 1.f / l;
  }
#pragma unroll
  for (int qi = 0; qi < 4; qi++) {
    const int q = q0 + qi * 16 + l15;
    if (q < NQTOK) {
      f16* op = o16 + ((size_t)(b * NQTOK + q)) * CDIM + h * 64 + l4 * 4;
#pragma unroll
      for (int df = 0; df < 4; df++) {
        f16x4_t ov = {(f16)(oacc[df][qi][0] * inv[qi]),
                      (f16)(oacc[df][qi][1] * inv[qi]),
                      (f16)(oacc[df][qi][2] * inv[qi]),
                      (f16)(oacc[df][qi][3] * inv[qi])};
        *(f16x4_t*)(op + df * 16) = ov;
      }
    }
  }
}

// ---------------------------------------------------------------------------
extern "C" void kernel_launch(void* const* d_in, const int* in_sizes, int n_in,
                              void* d_out, int out_size, void* d_ws, size_t ws_size,
                              hipStream_t stream) {
  const float* x      = (const float*)d_in[0];
  const float* cls    = (const float*)d_in[1];
  const float* Wq     = (const float*)d_in[2];
  const float* bq     = (const float*)d_in[3];
  const float* Wk     = (const float*)d_in[4];
  const float* bk     = (const float*)d_in[5];
  const float* Wv     = (const float*)d_in[6];
  const float* bv     = (const float*)d_in[7];
  const float* conv_q = (const float*)d_in[8];
  const float* conv_k = (const float*)d_in[9];
  const float* conv_v = (const float*)d_in[10];
  const float* lnq_w  = (const float*)d_in[11];
  const float* lnq_b  = (const float*)d_in[12];
  const float* lnk_w  = (const float*)d_in[13];
  const float* lnk_b  = (const float*)d_in[14];
  const float* lnv_w  = (const float*)d_in[15];
  const float* lnv_b  = (const float*)d_in[16];
  const float* Wproj  = (const float*)d_in[17];
  const float* bproj  = (const float*)d_in[18];

  // Workspace layout (bytes). Total = 124,747,776 B ≈ 124.7 MB.
  char* wsb = (char*)d_ws;
  f16*   Xt     = (f16*)(wsb + 0);           // 8*1792*768*2 = 22,020,096
  f16*   W16    = (f16*)(wsb + 22020096);    //  4,718,592
  f16*   q_lin  = (f16*)(wsb + 26738688);    // 8*768*1576*2 = 19,365,888
  f16*   k_lin  = (f16*)(wsb + 46104576);    // 19,365,888
  f16*   v_lin  = (f16*)(wsb + 65470464);    // 19,365,888
  f16*   k_pool = (f16*)(wsb + 84836352);    //  4,816,896
  f16*   v_pool = (f16*)(wsb + 89653248);    //  4,816,896
  f16*   Kh     = (f16*)(wsb + 94470144);    //  5,505,024
  f16*   Vht    = (f16*)(wsb + 99975168);    //  5,505,024
  f16*   q_pool = (f16*)(wsb + 105480192);   // 19,267,584 -> end 124,747,776
  f16*   Qh     = Xt;      // alias: Xt dead after QKV GEMM (sizes equal)
  f16*   o16    = v_lin;   // alias: v_lin (+294KB of dead k_pool) at proj;
                           // attn writes only rows < 12552

  f16* W16p = W16 + (size_t)3 * WELEM;

  // 1. convert weights to fp16
  convert4_kernel<<<dim3(576, 4), 256, 0, stream>>>(Wq, Wk, Wv, Wproj, W16);

  // 2. transpose+convert X (+cls as row 1568) -> Xt
  transpose_x_kernel<<<dim3(56, 24, BATCH), 256, 0, stream>>>(x, cls, Xt);

  // 3. fused QKV MFMA GEMM -> f16 lin buffers (stride 1576, col 1568 = cls)
  gemm_qkv_f16_kernel<<<1008, 256, 0, stream>>>(W16, Xt, bq, bk, bv, q_lin);

  // 4. cls rows of Qh/Kh
  cls_fill_kernel<<<BATCH, 768, 0, stream>>>(q_lin, k_lin, Qh, Kh);

  // 5. depthwise convs (q stride-1; k/v stride-2, 4 ch/block)
  dwconv_q_kernel<<<BATCH * CDIM, 256, 0, stream>>>(q_lin, conv_q, q_pool);
  dwconv_kv_kernel<<<dim3(BATCH * CDIM / 4, 2), 256, 0, stream>>>(
      k_lin, v_lin, conv_k, conv_v, k_pool, v_pool);

  // 6. fused LN + pack (q and k in one launch; v separate)
  ln_pack_qk2_kernel<<<dim3(62, BATCH), 256, 0, stream>>>(
      q_pool, k_pool, lnq_w, lnq_b, lnk_w, lnk_b, Qh, Kh);
  ln_pack_v_kernel<<<dim3(14, BATCH), 256, 0, stream>>>(v_pool, v_lin, lnv_w,
                                                        lnv_b, Vht);

  // 7. MFMA attention (64-q wave tiles) -> o16
  attn_mfma_kernel<<<dim3(7, NHEADS, BATCH), 256, 0, stream>>>(Qh, Kh, Vht,
                                                               o16);

  // 8. projection MFMA GEMM -> d_out
  float* xo = (float*)d_out;
  float* cls_o = (float*)d_out + (size_t)BATCH * CDIM * NSP;
  gemm_proj_f16_kernel<<<300, 256, 0, stream>>>(W16p, o16, bproj, xo, cls_o);
}

// Round 15
// 331.067 us; speedup vs baseline: 1.0785x; 1.0152x over previous
//
#include <hip/hip_runtime.h>

#define CDIM 768
#define BATCH 8
#define LDEPTH 8
#define HHEIGHT 14
#define WWIDTH 14
#define NSP 1568      // 8*14*14 spatial tokens (input / q)
#define NSPX 1576     // lin-buffer row stride: NSP + cls col (1568) + pad
#define NQTOK 1569    // +cls
#define NKSP 392      // 8*7*7 spatial tokens (k/v after pool)
#define NKTOK 393
#define NHEADS 12
#define HEADDIM 64
#define ATTN_SCALE 0.125f
#define LN_EPS 1e-6f
#define MTOK (BATCH * NQTOK)   // 12552 tokens for proj GEMM
#define NPAD_X 1792            // Xt padded rows per batch (7 tiles * 256)
#define WELEM (CDIM * CDIM)    // 589824
#define TQP 1792               // padded q tokens per (b,h)  (7*256)
#define TKP 448                // padded kv tokens per (b,h) (7*64)

typedef _Float16 f16;
typedef _Float16 f16x8_t __attribute__((ext_vector_type(8)));
typedef _Float16 f16x4_t __attribute__((ext_vector_type(4)));
typedef float f32x4_t __attribute__((ext_vector_type(4)));
typedef float f32x2_t __attribute__((ext_vector_type(2)));

// global -> LDS direct 16B copy (wave-uniform LDS base + lane*16)
__device__ __forceinline__ void gld_lds16(const void* g, void* l) {
  __builtin_amdgcn_global_load_lds(
      (const __attribute__((address_space(1))) void*)g,
      (__attribute__((address_space(3))) void*)l, 16, 0, 0);
}

// ---------------------------------------------------------------------------
// fp32 -> fp16 convert for the 4 weight matrices (one launch, grid.y = mat)
// ---------------------------------------------------------------------------
__global__ __launch_bounds__(256) void convert4_kernel(
    const float* __restrict__ s0, const float* __restrict__ s1,
    const float* __restrict__ s2, const float* __restrict__ s3,
    f16* __restrict__ dst) {
  const int mat = blockIdx.y;
  const float* src = (mat == 0) ? s0 : (mat == 1) ? s1 : (mat == 2) ? s2 : s3;
  int i = (blockIdx.x * 256 + threadIdx.x) * 4;
  if (i < WELEM) {
    float4 v = *(const float4*)&src[i];
    f16x4_t h = {(f16)v.x, (f16)v.y, (f16)v.z, (f16)v.w};
    *(f16x4_t*)&dst[(size_t)mat * WELEM + i] = h;
  }
}

// ---------------------------------------------------------------------------
// Transpose+convert X: (B,768,1568) f32 -> Xt (B,1792,768) f16.
// Row 1568 = class_token; rows >1568 = 0.
// ---------------------------------------------------------------------------
__global__ __launch_bounds__(256) void transpose_x_kernel(
    const float* __restrict__ X, const float* __restrict__ cls,
    f16* __restrict__ Xt) {
  __shared__ float t[32][33];
  const int b = blockIdx.z;
  const int k0 = blockIdx.y * 32;
  const int n0 = blockIdx.x * 32;   // grid.x = 56 (1792/32)
  const int tx = threadIdx.x & 31, ty = threadIdx.x >> 5;
#pragma unroll
  for (int i = 0; i < 4; i++) {
    int k = k0 + ty + i * 8;
    int n = n0 + tx;
    float v;
    if (n < NSP)
      v = X[((size_t)b * CDIM + k) * NSP + n];
    else if (n == NSP)
      v = cls[b * CDIM + k];
    else
      v = 0.f;
    t[ty + i * 8][tx] = v;
  }
  __syncthreads();
#pragma unroll
  for (int i = 0; i < 4; i++) {
    int n = n0 + ty + i * 8;
    Xt[((size_t)b * NPAD_X + n) * CDIM + k0 + tx] = (f16)t[tx][ty + i * 8];
  }
}

// ---------------------------------------------------------------------------
// Fused QKV MFMA GEMM. Block tile 128(m) x 256(n), BK=32, 4 waves, wave tile
// 64x128 (acc[4][8]). Double-buffered global_load_lds staging (next K-step's
// loads issued before current compute; ONE barrier per K-step). Source-side
// XOR swizzle matched by read-side XOR. 1D grid 1008, XCD swizzle: bid&7.
// ---------------------------------------------------------------------------
__global__ __launch_bounds__(256, 2) void gemm_qkv_f16_kernel(
    const f16* __restrict__ W16, const f16* __restrict__ Xt,
    const float* __restrict__ bq, const float* __restrict__ bk,
    const float* __restrict__ bv, f16* __restrict__ OutBase) {
  __shared__ __align__(16) f16 Asm[2][128 * 32];   // 16 KB
  __shared__ __align__(16) f16 Bsm[2][256 * 32];   // 32 KB

  const int bid = blockIdx.x;
  const int b = bid & 7;
  const int rem = bid >> 3;
  const int mat = rem / 42;
  const int rem2 = rem % 42;
  const int m0 = (rem2 / 7) * 128;
  const int n0 = (rem2 % 7) * 256;
  const int tid = threadIdx.x;
  const int lane = tid & 63;
  const int w = tid >> 6;
  const int wr = w >> 1, wc = w & 1;
  const int l15 = lane & 15, l4 = lane >> 4;

  const f16* A16 = W16 + (size_t)mat * WELEM;
  const float* bias = (mat == 0) ? bq : (mat == 1) ? bk : bv;
  f16* Out = OutBase + (size_t)mat * ((size_t)BATCH * CDIM * NSPX);

  const int srow = lane >> 2;
  const int skq = ((lane & 3) ^ ((lane >> 3) & 3)) * 8;
  const f16* Ag = A16 + (size_t)(m0 + w * 32 + srow) * CDIM + skq;
  const f16* Bg = Xt + ((size_t)b * NPAD_X + n0 + w * 64 + srow) * CDIM + skq;
  const int lAofs = w * 32 * 32;
  const int lBofs = w * 64 * 32;

  const int rsw = (l15 >> 1) & 3;
  const int kchunk = (l4 ^ rsw) * 8;

  f32x4_t acc[4][8];
#pragma unroll
  for (int i = 0; i < 4; i++)
#pragma unroll
    for (int j = 0; j < 8; j++) acc[i][j] = (f32x4_t){0.f, 0.f, 0.f, 0.f};

  // prologue: stage K-step 0 into buf 0
  gld_lds16(Ag, Asm[0] + lAofs);
  gld_lds16(Ag + 16 * CDIM, Asm[0] + lAofs + 16 * 32);
  gld_lds16(Bg, Bsm[0] + lBofs);
  gld_lds16(Bg + 16 * CDIM, Bsm[0] + lBofs + 16 * 32);
  gld_lds16(Bg + 32 * CDIM, Bsm[0] + lBofs + 32 * 32);
  gld_lds16(Bg + 48 * CDIM, Bsm[0] + lBofs + 48 * 32);
  __syncthreads();

  int cur = 0;
  for (int t = 0; t < CDIM / 32; ++t) {
    // issue next K-step's loads into the other buffer (hide under compute)
    if (t + 1 < CDIM / 32) {
      const int k1 = (t + 1) * 32;
      gld_lds16(Ag + k1, Asm[cur ^ 1] + lAofs);
      gld_lds16(Ag + 16 * CDIM + k1, Asm[cur ^ 1] + lAofs + 16 * 32);
      gld_lds16(Bg + k1, Bsm[cur ^ 1] + lBofs);
      gld_lds16(Bg + 16 * CDIM + k1, Bsm[cur ^ 1] + lBofs + 16 * 32);
      gld_lds16(Bg + 32 * CDIM + k1, Bsm[cur ^ 1] + lBofs + 32 * 32);
      gld_lds16(Bg + 48 * CDIM + k1, Bsm[cur ^ 1] + lBofs + 48 * 32);
    }
    const f16* As = Asm[cur];
    const f16* Bs = Bsm[cur];
    f16x8_t af[4];
#pragma unroll
    for (int mi = 0; mi < 4; mi++)
      af[mi] = *(const f16x8_t*)(As + (wr * 64 + mi * 16 + l15) * 32 + kchunk);
#pragma unroll
    for (int ni = 0; ni < 8; ni++) {
      f16x8_t bfv =
          *(const f16x8_t*)(Bs + (wc * 128 + ni * 16 + l15) * 32 + kchunk);
#pragma unroll
      for (int mi = 0; mi < 4; mi++)
        acc[mi][ni] = __builtin_amdgcn_mfma_f32_16x16x32_f16(
            af[mi], bfv, acc[mi][ni], 0, 0, 0);
    }
    __syncthreads();   // drains vmcnt (next buf staged) + lgkm (reads done)
    cur ^= 1;
  }

#pragma unroll
  for (int mi = 0; mi < 4; mi++) {
    const int mbase = m0 + wr * 64 + mi * 16 + l4 * 4;
#pragma unroll
    for (int ni = 0; ni < 8; ni++) {
      const int n = n0 + wc * 128 + ni * 16 + l15;
      if (n < NQTOK) {   // n == 1568 is the cls column
#pragma unroll
        for (int r = 0; r < 4; r++) {
          Out[((size_t)b * CDIM + mbase + r) * NSPX + n] =
              (f16)(acc[mi][ni][r] + bias[mbase + r]);
        }
      }
    }
  }
}

// ---------------------------------------------------------------------------
// Projection MFMA GEMM, same double-buffered 128x256 structure. 1D grid 300,
// bijective XCD swizzle (nwg=300: q=37, r=4).
// ---------------------------------------------------------------------------
__global__ __launch_bounds__(256, 2) void gemm_proj_f16_kernel(
    const f16* __restrict__ Wp16, const f16* __restrict__ o16,
    const float* __restrict__ bias, float* __restrict__ xo,
    float* __restrict__ cls_o) {
  __shared__ __align__(16) f16 Asm[2][128 * 32];
  __shared__ __align__(16) f16 Bsm[2][256 * 32];

  const int bid = blockIdx.x;
  const int xcd = bid & 7, pos_ = bid >> 3;
  const int base = (xcd < 4) ? xcd * 38 : 152 + (xcd - 4) * 37;
  const int wgid = base + pos_;
  const int m0 = (wgid / 50) * 128;
  const int n0 = (wgid % 50) * 256;
  const int tid = threadIdx.x;
  const int lane = tid & 63;
  const int w = tid >> 6;
  const int wr = w >> 1, wc = w & 1;
  const int l15 = lane & 15, l4 = lane >> 4;

  const int srow = lane >> 2;
  const int skq = ((lane & 3) ^ ((lane >> 3) & 3)) * 8;
  const f16* Ag = Wp16 + (size_t)(m0 + w * 32 + srow) * CDIM + skq;
  const f16* Bg = o16 + (size_t)(n0 + w * 64 + srow) * CDIM + skq;
  const int lAofs = w * 32 * 32;
  const int lBofs = w * 64 * 32;

  const int rsw = (l15 >> 1) & 3;
  const int kchunk = (l4 ^ rsw) * 8;

  f32x4_t acc[4][8];
#pragma unroll
  for (int i = 0; i < 4; i++)
#pragma unroll
    for (int j = 0; j < 8; j++) acc[i][j] = (f32x4_t){0.f, 0.f, 0.f, 0.f};

  gld_lds16(Ag, Asm[0] + lAofs);
  gld_lds16(Ag + 16 * CDIM, Asm[0] + lAofs + 16 * 32);
  gld_lds16(Bg, Bsm[0] + lBofs);
  gld_lds16(Bg + 16 * CDIM, Bsm[0] + lBofs + 16 * 32);
  gld_lds16(Bg + 32 * CDIM, Bsm[0] + lBofs + 32 * 32);
  gld_lds16(Bg + 48 * CDIM, Bsm[0] + lBofs + 48 * 32);
  __syncthreads();

  int cur = 0;
  for (int t = 0; t < CDIM / 32; ++t) {
    if (t + 1 < CDIM / 32) {
      const int k1 = (t + 1) * 32;
      gld_lds16(Ag + k1, Asm[cur ^ 1] + lAofs);
      gld_lds16(Ag + 16 * CDIM + k1, Asm[cur ^ 1] + lAofs + 16 * 32);
      gld_lds16(Bg + k1, Bsm[cur ^ 1] + lBofs);
      gld_lds16(Bg + 16 * CDIM + k1, Bsm[cur ^ 1] + lBofs + 16 * 32);
      gld_lds16(Bg + 32 * CDIM + k1, Bsm[cur ^ 1] + lBofs + 32 * 32);
      gld_lds16(Bg + 48 * CDIM + k1, Bsm[cur ^ 1] + lBofs + 48 * 32);
    }
    const f16* As = Asm[cur];
    const f16* Bs = Bsm[cur];
    f16x8_t af[4];
#pragma unroll
    for (int mi = 0; mi < 4; mi++)
      af[mi] = *(const f16x8_t*)(As + (wr * 64 + mi * 16 + l15) * 32 + kchunk);
#pragma unroll
    for (int ni = 0; ni < 8; ni++) {
      f16x8_t bfv =
          *(const f16x8_t*)(Bs + (wc * 128 + ni * 16 + l15) * 32 + kchunk);
#pragma unroll
      for (int mi = 0; mi < 4; mi++)
        acc[mi][ni] = __builtin_amdgcn_mfma_f32_16x16x32_f16(
            af[mi], bfv, acc[mi][ni], 0, 0, 0);
    }
    __syncthreads();
    cur ^= 1;
  }

#pragma unroll
  for (int ni = 0; ni < 8; ni++) {
    const int tok = n0 + wc * 128 + ni * 16 + l15;
    if (tok < MTOK) {
      const int bb = tok / NQTOK;
      const int nn = tok % NQTOK;
#pragma unroll
      for (int mi = 0; mi < 4; mi++) {
        const int mbase = m0 + wr * 64 + mi * 16 + l4 * 4;
#pragma unroll
        for (int r = 0; r < 4; r++) {
          float v = acc[mi][ni][r] + bias[mbase + r];
          if (nn == 0)
            cls_o[bb * CDIM + mbase + r] = v;
          else
            xo[((size_t)bb * CDIM + mbase + r) * (size_t)NSP + nn - 1] = v;
        }
      }
    }
  }
}

// ---------------------------------------------------------------------------
// Depthwise conv for q (stride 1, out 8x14x14). One block per (b,c) plane.
// L-fastest padded LDS volume (round-12 verified).
// ---------------------------------------------------------------------------
__global__ __launch_bounds__(256) void dwconv_q_kernel(
    const f16* __restrict__ q_lin, const float* __restrict__ cq,
    f16* __restrict__ q_pool) {
  __shared__ float vol[16 * 196];   // 12,544 B
  __shared__ float wsm[27];
  const int c = blockIdx.x % CDIM;
  const int b = blockIdx.x / CDIM;
  const f16* xb = q_lin + ((size_t)b * CDIM + c) * (size_t)NSPX;

  for (int i = threadIdx.x; i < 16 * 196; i += 256) vol[i] = 0.f;
  if (threadIdx.x < 27) wsm[threadIdx.x] = cq[c * 27 + threadIdx.x];
  __syncthreads();
  for (int i = threadIdx.x; i < NSP; i += 256) {
    int li = i / 196;
    int r = i - li * 196;
    int hi = r / 14;
    int wi = r - hi * 14;
    vol[(wi + 1) * 196 + (hi + 1) * 12 + (li + 1)] = (float)xb[i];
  }
  __syncthreads();

  if (threadIdx.x < 196) {
    const int ho = threadIdx.x / 14;
    const int wo = threadIdx.x - ho * 14;
    float sums[8];
#pragma unroll
    for (int lo = 0; lo < 8; lo++) sums[lo] = 0.f;
#pragma unroll
    for (int kh = 0; kh < 3; kh++) {
#pragma unroll
      for (int kw = 0; kw < 3; kw++) {
        const float* p = &vol[(wo + kw) * 196 + (ho + kh) * 12];
        float z[10];
        *(f32x4_t*)&z[0] = *(const f32x4_t*)p;
        *(f32x4_t*)&z[4] = *(const f32x4_t*)(p + 4);
        *(f32x2_t*)&z[8] = *(const f32x2_t*)(p + 8);
        const float w0 = wsm[0 + kh * 3 + kw];
        const float w1 = wsm[9 + kh * 3 + kw];
        const float w2 = wsm[18 + kh * 3 + kw];
#pragma unroll
        for (int lo = 0; lo < 8; lo++) {
          sums[lo] = fmaf(z[lo], w0, sums[lo]);
          sums[lo] = fmaf(z[lo + 1], w1, sums[lo]);
          sums[lo] = fmaf(z[lo + 2], w2, sums[lo]);
        }
      }
    }
    f16* ob = q_pool + ((size_t)b * CDIM + c) * (size_t)NSP;
    const int hw = ho * 14 + wo;
#pragma unroll
    for (int lo = 0; lo < 8; lo++) ob[lo * 196 + hw] = (f16)sums[lo];
  }
}

// ---------------------------------------------------------------------------
// Depthwise conv for k/v (stride 2, out 8x7x7). 4 channels per block.
// ---------------------------------------------------------------------------
__global__ __launch_bounds__(256) void dwconv_kv_kernel(
    const f16* __restrict__ k_lin, const f16* __restrict__ v_lin,
    const float* __restrict__ ck, const float* __restrict__ cv,
    f16* __restrict__ k_pool, f16* __restrict__ v_pool) {
  __shared__ float vol4[4][16 * 196];   // 50,176 B
  __shared__ float wsm4[4][27];
  const int which = blockIdx.y;
  const f16* X = which ? v_lin : k_lin;
  const float* wconv = which ? cv : ck;
  f16* Out = which ? v_pool : k_pool;
  const int cg = blockIdx.x % (CDIM / 4);
  const int b = blockIdx.x / (CDIM / 4);
  const int c0 = cg * 4;
  const f16* xb0 = X + ((size_t)b * CDIM + c0) * (size_t)NSPX;

  for (int i = threadIdx.x; i < 4 * 16 * 196; i += 256)
    ((float*)vol4)[i] = 0.f;
  if (threadIdx.x < 108) {
    int ch = threadIdx.x / 27;
    int j = threadIdx.x - ch * 27;
    wsm4[ch][j] = wconv[(c0 + ch) * 27 + j];
  }
  __syncthreads();
  for (int i = threadIdx.x; i < 4 * NSP; i += 256) {
    int ch = i / NSP;
    int j = i - ch * NSP;
    int li = j / 196;
    int r = j - li * 196;
    int hi = r / 14;
    int wi = r - hi * 14;
    vol4[ch][(wi + 1) * 196 + (hi + 1) * 12 + (li + 1)] =
        (float)xb0[(size_t)ch * NSPX + j];
  }
  __syncthreads();

  if (threadIdx.x < 196) {
    const int ch = threadIdx.x / 49;
    const int p2 = threadIdx.x - ch * 49;
    const int ho = p2 / 7;
    const int wo = p2 - ho * 7;
    const float* vol = vol4[ch];
    const float* wsm = wsm4[ch];
    float sums[8];
#pragma unroll
    for (int lo = 0; lo < 8; lo++) sums[lo] = 0.f;
#pragma unroll
    for (int kh = 0; kh < 3; kh++) {
#pragma unroll
      for (int kw = 0; kw < 3; kw++) {
        const float* p = &vol[(wo * 2 + kw) * 196 + (ho * 2 + kh) * 12];
        float z[10];
        *(f32x4_t*)&z[0] = *(const f32x4_t*)p;
        *(f32x4_t*)&z[4] = *(const f32x4_t*)(p + 4);
        *(f32x2_t*)&z[8] = *(const f32x2_t*)(p + 8);
        const float w0 = wsm[0 + kh * 3 + kw];
        const float w1 = wsm[9 + kh * 3 + kw];
        const float w2 = wsm[18 + kh * 3 + kw];
#pragma unroll
        for (int lo = 0; lo < 8; lo++) {
          sums[lo] = fmaf(z[lo], w0, sums[lo]);
          sums[lo] = fmaf(z[lo + 1], w1, sums[lo]);
          sums[lo] = fmaf(z[lo + 2], w2, sums[lo]);
        }
      }
    }
    f16* ob = Out + ((size_t)b * CDIM + c0 + ch) * (size_t)NKSP;
    const int hw = ho * 7 + wo;
#pragma unroll
    for (int lo = 0; lo < 8; lo++) ob[lo * 49 + hw] = (f16)sums[lo];
  }
}

// ---------------------------------------------------------------------------
// Fused LayerNorm + head-pack for q AND k + cls rows, one launch:
// grid (63, B); bx<49 -> q tile, bx<62 -> k tile, bx==62 -> cls fill.
// ---------------------------------------------------------------------------
__global__ __launch_bounds__(256) void ln_pack_qk2_kernel(
    const f16* __restrict__ qp, const f16* __restrict__ kp,
    const f16* __restrict__ qlin, const f16* __restrict__ klin,
    const float* __restrict__ lnq_w, const float* __restrict__ lnq_b,
    const float* __restrict__ lnk_w, const float* __restrict__ lnk_b,
    f16* __restrict__ Qh, f16* __restrict__ Kh) {
  const int bx = blockIdx.x;
  const int b = blockIdx.y;
  const int tid = threadIdx.x;

  if (bx == 62) {   // cls fill: t=0 rows of Qh/Kh from lin cls column
#pragma unroll
    for (int cc = 0; cc < 3; cc++) {
      const int c = tid + cc * 256;
      Qh[(((size_t)(b * NHEADS + (c >> 6))) * TQP) * 64 + (c & 63)] =
          qlin[((size_t)b * CDIM + c) * NSPX + NSP];
      Kh[(((size_t)(b * NHEADS + (c >> 6))) * TKP) * 64 + (c & 63)] =
          klin[((size_t)b * CDIM + c) * NSPX + NSP];
    }
    return;
  }

  const bool isq = bx < 49;
  const f16* xp = isq ? qp : kp;
  const float* ln_w = isq ? lnq_w : lnk_w;
  const float* ln_b = isq ? lnq_b : lnk_b;
  f16* OutH = isq ? Qh : Kh;
  const int np = isq ? NSP : NKSP;
  const int tp = isq ? TQP : TKP;
  const int p0 = (isq ? bx : bx - 49) * 32;
  const int pl = tid & 31;
  const int grp = tid >> 5;
  const int pos = p0 + pl;
  const bool act = pos < np;
  const f16* Xb = xp + (size_t)b * CDIM * (size_t)np;

  __shared__ __align__(16) f16 tile[32][784];
  __shared__ float r1[8][33], r2[8][33];
  __shared__ float smean[32], srstd[32];

  const int swz = (pl & 7) << 3;
  float s1 = 0.f, s2 = 0.f;
  for (int cc = 0; cc < 12; cc++) {
    const int c0 = grp * 96 + cc * 8;
    f16x8_t hv;
#pragma unroll
    for (int i = 0; i < 8; i++) {
      f16 h = act ? Xb[(size_t)(c0 + i) * np + pos] : (f16)0.f;
      hv[i] = h;
      float v = (float)h;
      s1 += v;
      s2 = fmaf(v, v, s2);
    }
    *(f16x8_t*)&tile[pl][c0 ^ swz] = hv;
  }
  r1[grp][pl] = s1;
  r2[grp][pl] = s2;
  __syncthreads();
  if (tid < 32) {
    float t1 = 0.f, t2 = 0.f;
#pragma unroll
    for (int g = 0; g < 8; g++) { t1 += r1[g][tid]; t2 += r2[g][tid]; }
    float mean = t1 * (1.f / 768.f);
    float var = t2 * (1.f / 768.f) - mean * mean;
    smean[tid] = mean;
    srstd[tid] = rsqrtf(var + LN_EPS);
  }
  __syncthreads();

  const int tl = tid >> 3, d8 = (tid & 7) * 8;
  const float mean = smean[tl], rstd = srstd[tl];
  const bool wv = (p0 + tl) < np;
  const int tswz = (tl & 7) << 3;
#pragma unroll
  for (int h = 0; h < NHEADS; h++) {
    const int c = h * 64 + d8;
    f16x8_t raw = *(const f16x8_t*)&tile[tl][c ^ tswz];
    float4 w1 = *(const float4*)&ln_w[c];
    float4 w2 = *(const float4*)&ln_w[c + 4];
    float4 b1 = *(const float4*)&ln_b[c];
    float4 b2 = *(const float4*)&ln_b[c + 4];
    f16x8_t ov;
    ov[0] = (f16)(((float)raw[0] - mean) * rstd * w1.x + b1.x);
    ov[1] = (f16)(((float)raw[1] - mean) * rstd * w1.y + b1.y);
    ov[2] = (f16)(((float)raw[2] - mean) * rstd * w1.z + b1.z);
    ov[3] = (f16)(((float)raw[3] - mean) * rstd * w1.w + b1.w);
    ov[4] = (f16)(((float)raw[4] - mean) * rstd * w2.x + b2.x);
    ov[5] = (f16)(((float)raw[5] - mean) * rstd * w2.y + b2.y);
    ov[6] = (f16)(((float)raw[6] - mean) * rstd * w2.z + b2.z);
    ov[7] = (f16)(((float)raw[7] - mean) * rstd * w2.w + b2.w);
    if (wv)
      *(uint4*)(OutH +
                (((size_t)(b * NHEADS + h)) * (size_t)tp + (p0 + tl + 1)) * 64 +
                d8) = *(uint4*)&ov;
  }
}

// ---------------------------------------------------------------------------
// Fused LayerNorm + transpose-pack for v. cls (t=0) raw from v_lin col NSP.
// ---------------------------------------------------------------------------
__global__ __launch_bounds__(256) void ln_pack_v_kernel(
    const f16* __restrict__ vp, const f16* __restrict__ vlin,
    const float* __restrict__ ln_w, const float* __restrict__ ln_b,
    f16* __restrict__ Vht) {
  const int b = blockIdx.y;
  const int t0 = blockIdx.x * 32;
  const int tid = threadIdx.x;
  const int pl = tid & 31;
  const int grp = tid >> 5;
  const int t = t0 + pl;
  const int pos = t - 1;
  const bool isv = (t >= 1) && (t < NKTOK);
  const f16* Vb = vp + (size_t)b * CDIM * (size_t)NKSP;

  __shared__ float r1[8][33], r2[8][33];
  __shared__ float smean[32], srstd[32];
  __shared__ __align__(16) f16 vtile[128][40];

  float s1 = 0.f, s2 = 0.f;
  if (isv) {
    for (int c = grp; c < CDIM; c += 8) {
      float v = (float)Vb[(size_t)c * NKSP + pos];
      s1 += v;
      s2 = fmaf(v, v, s2);
    }
  }
  r1[grp][pl] = s1;
  r2[grp][pl] = s2;
  __syncthreads();
  if (tid < 32) {
    float t1 = 0.f, t2 = 0.f;
#pragma unroll
    for (int g = 0; g < 8; g++) { t1 += r1[g][tid]; t2 += r2[g][tid]; }
    float mean = t1 * (1.f / 768.f);
    float var = t2 * (1.f / 768.f) - mean * mean;
    smean[tid] = mean;
    srstd[tid] = rsqrtf(var + LN_EPS);
  }
  __syncthreads();
  const float mean = smean[pl], rstd = srstd[pl];

  for (int cc = 0; cc < 6; cc++) {
#pragma unroll
    for (int i = 0; i < 16; i++) {
      int cl = grp * 16 + i;
      int c = cc * 128 + cl;
      float outv;
      if (isv)
        outv = ((float)Vb[(size_t)c * NKSP + pos] - mean) * rstd * ln_w[c] +
               ln_b[c];
      else if (t == 0)
        outv = (float)vlin[((size_t)b * CDIM + c) * NSPX + NSP];
      else
        outv = 0.f;
      vtile[cl][pl] = (f16)outv;
    }
    __syncthreads();
#pragma unroll
    for (int it = 0; it < 2; it++) {
      int idx = it * 256 + tid;
      int cl = idx >> 2, t8 = (idx & 3) * 8;
      uint4 vv = *(const uint4*)&vtile[cl][t8];
      *(uint4*)(Vht + ((size_t)b * CDIM + cc * 128 + cl) * (size_t)TKP + t0 +
                t8) = vv;
    }
    __syncthreads();
  }
}

// ---------------------------------------------------------------------------
// MFMA flash attention. Grid (7, 12, 8), 256 threads = 4 waves; wave tile
// 64 q x 64 keys (bq[4][2], sacc[4][4], oacc[4][4]).
// ---------------------------------------------------------------------------
__global__ __launch_bounds__(256) void attn_mfma_kernel(
    const f16* __restrict__ Qh, const f16* __restrict__ Kh,
    const f16* __restrict__ Vht, f16* __restrict__ o16) {
  __shared__ __align__(16) f16 Ks[64 * 72];   // [key][d], pad 8
  __shared__ __align__(16) f16 Vt[64 * 72];   // [d][key], pad 8
  const int qt = blockIdx.x, h = blockIdx.y, b = blockIdx.z;
  const int tid = threadIdx.x;
  const int lane = tid & 63;
  const int w = tid >> 6;
  const int l15 = lane & 15, l4 = lane >> 4;
  const int q0 = qt * 256 + w * 64;

  const f16* Qp = Qh + ((size_t)(b * NHEADS + h) * TQP) * 64;
  const f16* Kp = Kh + ((size_t)(b * NHEADS + h) * TKP) * 64;
  const f16* Vp = Vht + ((size_t)(b * NHEADS + h) * 64) * TKP;

  f16x8_t bq[4][2];
#pragma unroll
  for (int qi = 0; qi < 4; qi++)
#pragma unroll
    for (int kf = 0; kf < 2; kf++)
      bq[qi][kf] = *(const f16x8_t*)(Qp + (size_t)(q0 + qi * 16 + l15) * 64 +
                                     kf * 32 + l4 * 8);

  f32x4_t oacc[4][4];
#pragma unroll
  for (int df = 0; df < 4; df++)
#pragma unroll
    for (int qi = 0; qi < 4; qi++) oacc[df][qi] = (f32x4_t){0.f, 0.f, 0.f, 0.f};
  float mrow[4] = {-1e30f, -1e30f, -1e30f, -1e30f};
  float lrow[4] = {0.f, 0.f, 0.f, 0.f};

  const int sr = tid >> 2, sc = (tid & 3) * 16;

  for (int kv0 = 0; kv0 < TKP; kv0 += 64) {
    const f16* kg = Kp + (size_t)(kv0 + sr) * 64 + sc;
    uint4 kl0 = *(const uint4*)kg;
    uint4 kl1 = *(const uint4*)(kg + 8);
    const f16* vg = Vp + (size_t)sr * TKP + kv0 + sc;
    uint4 vl0 = *(const uint4*)vg;
    uint4 vl1 = *(const uint4*)(vg + 8);
    __syncthreads();
    *(uint4*)(Ks + sr * 72 + sc) = kl0;
    *(uint4*)(Ks + sr * 72 + sc + 8) = kl1;
    *(uint4*)(Vt + sr * 72 + sc) = vl0;
    *(uint4*)(Vt + sr * 72 + sc + 8) = vl1;
    __syncthreads();

    // ---- S^T = K * Q^T ----
    f32x4_t sacc[4][4];
#pragma unroll
    for (int ki = 0; ki < 4; ki++)
#pragma unroll
      for (int qi = 0; qi < 4; qi++)
        sacc[ki][qi] = (f32x4_t){0.f, 0.f, 0.f, 0.f};
#pragma unroll
    for (int kf = 0; kf < 2; kf++) {
#pragma unroll
      for (int ki = 0; ki < 4; ki++) {
        f16x8_t ak =
            *(const f16x8_t*)(Ks + (ki * 16 + l15) * 72 + kf * 32 + l4 * 8);
#pragma unroll
        for (int qi = 0; qi < 4; qi++)
          sacc[ki][qi] = __builtin_amdgcn_mfma_f32_16x16x32_f16(
              ak, bq[qi][kf], sacc[ki][qi], 0, 0, 0);
      }
    }

    // ---- scale + mask + online softmax ----
    float pmax[4] = {-1e30f, -1e30f, -1e30f, -1e30f};
#pragma unroll
    for (int ki = 0; ki < 4; ki++) {
      const int keyb = kv0 + ki * 16 + l4 * 4;
#pragma unroll
      for (int qi = 0; qi < 4; qi++) {
#pragma unroll
        for (int rr = 0; rr < 4; rr++) {
          float s = sacc[ki][qi][rr] * ATTN_SCALE;
          if (keyb + rr >= NKTOK) s = -1e30f;
          sacc[ki][qi][rr] = s;
          pmax[qi] = fmaxf(pmax[qi], s);
        }
      }
    }
#pragma unroll
    for (int qi = 0; qi < 4; qi++) {
      pmax[qi] = fmaxf(pmax[qi], __shfl_xor(pmax[qi], 16, 64));
      pmax[qi] = fmaxf(pmax[qi], __shfl_xor(pmax[qi], 32, 64));
      float mnew = fmaxf(mrow[qi], pmax[qi]);
      float alpha = __expf(mrow[qi] - mnew);
      mrow[qi] = mnew;
      lrow[qi] *= alpha;
#pragma unroll
      for (int df = 0; df < 4; df++) {
        oacc[df][qi][0] *= alpha;
        oacc[df][qi][1] *= alpha;
        oacc[df][qi][2] *= alpha;
        oacc[df][qi][3] *= alpha;
      }
    }

    // ---- per-ki P + PV ----
#pragma unroll
    for (int ki = 0; ki < 4; ki++) {
      f16x4_t pb[4];
#pragma unroll
      for (int qi = 0; qi < 4; qi++) {
        float p0 = __expf(sacc[ki][qi][0] - mrow[qi]);
        float p1 = __expf(sacc[ki][qi][1] - mrow[qi]);
        float p2 = __expf(sacc[ki][qi][2] - mrow[qi]);
        float p3 = __expf(sacc[ki][qi][3] - mrow[qi]);
        lrow[qi] += p0 + p1 + p2 + p3;
        f16x4_t pv = {(f16)p0, (f16)p1, (f16)p2, (f16)p3};
        pb[qi] = pv;
      }
#pragma unroll
      for (int df = 0; df < 4; df++) {
        f16x4_t av =
            *(const f16x4_t*)(Vt + (df * 16 + l15) * 72 + ki * 16 + l4 * 4);
#pragma unroll
        for (int qi = 0; qi < 4; qi++)
          oacc[df][qi] = __builtin_amdgcn_mfma_f32_16x16x16f16(
              av, pb[qi], oacc[df][qi], 0, 0, 0);
      }
    }
  }

  float inv[4];
#pragma unroll
  for (int qi = 0; qi < 4; qi++) {
    float l = lrow[qi];
    l += __shfl_xor(l, 16, 64);
    l += __shfl_xor(l, 32, 64);
    inv[qi] = 1.f / l;
  }
#pragma unroll
  for (int qi = 0; qi < 4; qi++) {
    const int q = q0 + qi * 16 + l15;
    if (q < NQTOK) {
      f16* op = o16 + ((size_t)(b * NQTOK + q)) * CDIM + h * 64 + l4 * 4;
#pragma unroll
      for (int df = 0; df < 4; df++) {
        f16x4_t ov = {(f16)(oacc[df][qi][0] * inv[qi]),
                      (f16)(oacc[df][qi][1] * inv[qi]),
                      (f16)(oacc[df][qi][2] * inv[qi]),
                      (f16)(oacc[df][qi][3] * inv[qi])};
        *(f16x4_t*)(op + df * 16) = ov;
      }
    }
  }
}

// ---------------------------------------------------------------------------
extern "C" void kernel_launch(void* const* d_in, const int* in_sizes, int n_in,
                              void* d_out, int out_size, void* d_ws, size_t ws_size,
                              hipStream_t stream) {
  const float* x      = (const float*)d_in[0];
  const float* cls    = (const float*)d_in[1];
  const float* Wq     = (const float*)d_in[2];
  const float* bq     = (const float*)d_in[3];
  const float* Wk     = (const float*)d_in[4];
  const float* bk     = (const float*)d_in[5];
  const float* Wv     = (const float*)d_in[6];
  const float* bv     = (const float*)d_in[7];
  const float* conv_q = (const float*)d_in[8];
  const float* conv_k = (const float*)d_in[9];
  const float* conv_v = (const float*)d_in[10];
  const float* lnq_w  = (const float*)d_in[11];
  const float* lnq_b  = (const float*)d_in[12];
  const float* lnk_w  = (const float*)d_in[13];
  const float* lnk_b  = (const float*)d_in[14];
  const float* lnv_w  = (const float*)d_in[15];
  const float* lnv_b  = (const float*)d_in[16];
  const float* Wproj  = (const float*)d_in[17];
  const float* bproj  = (const float*)d_in[18];

  // Workspace layout (bytes). Total = 124,747,776 B ≈ 124.7 MB.
  char* wsb = (char*)d_ws;
  f16*   Xt     = (f16*)(wsb + 0);           // 8*1792*768*2 = 22,020,096
  f16*   W16    = (f16*)(wsb + 22020096);    //  4,718,592
  f16*   q_lin  = (f16*)(wsb + 26738688);    // 8*768*1576*2 = 19,365,888
  f16*   k_lin  = (f16*)(wsb + 46104576);    // 19,365,888
  f16*   v_lin  = (f16*)(wsb + 65470464);    // 19,365,888
  f16*   k_pool = (f16*)(wsb + 84836352);    //  4,816,896
  f16*   v_pool = (f16*)(wsb + 89653248);    //  4,816,896
  f16*   Kh     = (f16*)(wsb + 94470144);    //  5,505,024
  f16*   Vht    = (f16*)(wsb + 99975168);    //  5,505,024
  f16*   q_pool = (f16*)(wsb + 105480192);   // 19,267,584 -> end 124,747,776
  f16*   Qh     = Xt;      // alias: Xt dead after QKV GEMM (sizes equal)
  f16*   o16    = v_lin;   // alias: v_lin (+294KB of dead k_pool) at proj;
                           // attn writes only rows < 12552

  f16* W16p = W16 + (size_t)3 * WELEM;

  // 1. convert weights to fp16
  convert4_kernel<<<dim3(576, 4), 256, 0, stream>>>(Wq, Wk, Wv, Wproj, W16);

  // 2. transpose+convert X (+cls as row 1568) -> Xt
  transpose_x_kernel<<<dim3(56, 24, BATCH), 256, 0, stream>>>(x, cls, Xt);

  // 3. fused QKV MFMA GEMM (double-buffered) -> f16 lin buffers
  gemm_qkv_f16_kernel<<<1008, 256, 0, stream>>>(W16, Xt, bq, bk, bv, q_lin);

  // 4. depthwise convs (q stride-1; k/v stride-2, 4 ch/block)
  dwconv_q_kernel<<<BATCH * CDIM, 256, 0, stream>>>(q_lin, conv_q, q_pool);
  dwconv_kv_kernel<<<dim3(BATCH * CDIM / 4, 2), 256, 0, stream>>>(
      k_lin, v_lin, conv_k, conv_v, k_pool, v_pool);

  // 5. fused LN + pack (q, k, and cls rows in one launch; v separate)
  ln_pack_qk2_kernel<<<dim3(63, BATCH), 256, 0, stream>>>(
      q_pool, k_pool, q_lin, k_lin, lnq_w, lnq_b, lnk_w, lnk_b, Qh, Kh);
  ln_pack_v_kernel<<<dim3(14, BATCH), 256, 0, stream>>>(v_pool, v_lin, lnv_w,
                                                        lnv_b, Vht);

  // 6. MFMA attention (64-q wave tiles) -> o16
  attn_mfma_kernel<<<dim3(7, NHEADS, BATCH), 256, 0, stream>>>(Qh, Kh, Vht,
                                                               o16);

  // 7. projection MFMA GEMM (double-buffered) -> d_out
  float* xo = (float*)d_out;
  float* cls_o = (float*)d_out + (size_t)BATCH * CDIM * NSP;
  gemm_proj_f16_kernel<<<300, 256, 0, stream>>>(W16p, o16, bproj, xo, cls_o);
}

// Round 16
// 326.615 us; speedup vs baseline: 1.0932x; 1.0136x over previous
//
#include <hip/hip_runtime.h>

#define CDIM 768
#define BATCH 8
#define LDEPTH 8
#define HHEIGHT 14
#define WWIDTH 14
#define NSP 1568      // 8*14*14 spatial tokens (input / q)
#define NSPX 1576     // lin-buffer row stride: NSP + cls col (1568) + pad
#define NQTOK 1569    // +cls
#define NKSP 392      // 8*7*7 spatial tokens (k/v after pool)
#define NKTOK 393
#define NHEADS 12
#define HEADDIM 64
#define ATTN_SCALE 0.125f
#define LN_EPS 1e-6f
#define MTOK (BATCH * NQTOK)   // 12552 tokens for proj GEMM
#define NPAD_X 1792            // Xt padded rows per batch (7 tiles * 256)
#define WELEM (CDIM * CDIM)    // 589824
#define TQP 1792               // padded q tokens per (b,h)  (7*256)
#define TKP 448                // padded kv tokens per (b,h) (7*64)

typedef _Float16 f16;
typedef _Float16 f16x8_t __attribute__((ext_vector_type(8)));
typedef _Float16 f16x4_t __attribute__((ext_vector_type(4)));
typedef float f32x4_t __attribute__((ext_vector_type(4)));
typedef float f32x2_t __attribute__((ext_vector_type(2)));

// global -> LDS direct 16B copy (wave-uniform LDS base + lane*16)
__device__ __forceinline__ void gld_lds16(const void* g, void* l) {
  __builtin_amdgcn_global_load_lds(
      (const __attribute__((address_space(1))) void*)g,
      (__attribute__((address_space(3))) void*)l, 16, 0, 0);
}

// ---------------------------------------------------------------------------
// fp32 -> fp16 convert for the 4 weight matrices (one launch, grid.y = mat)
// ---------------------------------------------------------------------------
__global__ __launch_bounds__(256) void convert4_kernel(
    const float* __restrict__ s0, const float* __restrict__ s1,
    const float* __restrict__ s2, const float* __restrict__ s3,
    f16* __restrict__ dst) {
  const int mat = blockIdx.y;
  const float* src = (mat == 0) ? s0 : (mat == 1) ? s1 : (mat == 2) ? s2 : s3;
  int i = (blockIdx.x * 256 + threadIdx.x) * 4;
  if (i < WELEM) {
    float4 v = *(const float4*)&src[i];
    f16x4_t h = {(f16)v.x, (f16)v.y, (f16)v.z, (f16)v.w};
    *(f16x4_t*)&dst[(size_t)mat * WELEM + i] = h;
  }
}

// ---------------------------------------------------------------------------
// Transpose+convert X: (B,768,1568) f32 -> Xt (B,1792,768) f16.
// Row 1568 = class_token; rows >1568 = 0.
// ---------------------------------------------------------------------------
__global__ __launch_bounds__(256) void transpose_x_kernel(
    const float* __restrict__ X, const float* __restrict__ cls,
    f16* __restrict__ Xt) {
  __shared__ float t[32][33];
  const int b = blockIdx.z;
  const int k0 = blockIdx.y * 32;
  const int n0 = blockIdx.x * 32;   // grid.x = 56 (1792/32)
  const int tx = threadIdx.x & 31, ty = threadIdx.x >> 5;
#pragma unroll
  for (int i = 0; i < 4; i++) {
    int k = k0 + ty + i * 8;
    int n = n0 + tx;
    float v;
    if (n < NSP)
      v = X[((size_t)b * CDIM + k) * NSP + n];
    else if (n == NSP)
      v = cls[b * CDIM + k];
    else
      v = 0.f;
    t[ty + i * 8][tx] = v;
  }
  __syncthreads();
#pragma unroll
  for (int i = 0; i < 4; i++) {
    int n = n0 + ty + i * 8;
    Xt[((size_t)b * NPAD_X + n) * CDIM + k0 + tx] = (f16)t[tx][ty + i * 8];
  }
}

// ---------------------------------------------------------------------------
// Fused QKV MFMA GEMM (round-12 verified optimum). Block tile 128x256, BK=32,
// 4 waves, wave tile 64x128 (acc[4][8]). global_load_lds staging, source-side
// XOR swizzle matched by read-side XOR. 1D grid 1008, XCD swizzle: bid&7.
// ---------------------------------------------------------------------------
__global__ __launch_bounds__(256, 2) void gemm_qkv_f16_kernel(
    const f16* __restrict__ W16, const f16* __restrict__ Xt,
    const float* __restrict__ bq, const float* __restrict__ bk,
    const float* __restrict__ bv, f16* __restrict__ OutBase) {
  __shared__ __align__(16) f16 Asm[128 * 32];   // 8 KB
  __shared__ __align__(16) f16 Bsm[256 * 32];   // 16 KB

  const int bid = blockIdx.x;
  const int b = bid & 7;
  const int rem = bid >> 3;
  const int mat = rem / 42;
  const int rem2 = rem % 42;
  const int m0 = (rem2 / 7) * 128;
  const int n0 = (rem2 % 7) * 256;
  const int tid = threadIdx.x;
  const int lane = tid & 63;
  const int w = tid >> 6;
  const int wr = w >> 1, wc = w & 1;
  const int l15 = lane & 15, l4 = lane >> 4;

  const f16* A16 = W16 + (size_t)mat * WELEM;
  const float* bias = (mat == 0) ? bq : (mat == 1) ? bk : bv;
  f16* Out = OutBase + (size_t)mat * ((size_t)BATCH * CDIM * NSPX);

  const int srow = lane >> 2;
  const int skq = ((lane & 3) ^ ((lane >> 3) & 3)) * 8;
  const f16* Ag = A16 + (size_t)(m0 + w * 32 + srow) * CDIM + skq;
  const f16* Bg = Xt + ((size_t)b * NPAD_X + n0 + w * 64 + srow) * CDIM + skq;
  f16* lA = Asm + w * 32 * 32;
  f16* lB = Bsm + w * 64 * 32;

  const int rsw = (l15 >> 1) & 3;
  const int kchunk = (l4 ^ rsw) * 8;

  f32x4_t acc[4][8];
#pragma unroll
  for (int i = 0; i < 4; i++)
#pragma unroll
    for (int j = 0; j < 8; j++) acc[i][j] = (f32x4_t){0.f, 0.f, 0.f, 0.f};

  for (int k0 = 0; k0 < CDIM; k0 += 32) {
    gld_lds16(Ag + k0, lA);
    gld_lds16(Ag + 16 * CDIM + k0, lA + 16 * 32);
    gld_lds16(Bg + k0, lB);
    gld_lds16(Bg + 16 * CDIM + k0, lB + 16 * 32);
    gld_lds16(Bg + 32 * CDIM + k0, lB + 32 * 32);
    gld_lds16(Bg + 48 * CDIM + k0, lB + 48 * 32);
    __syncthreads();
    f16x8_t af[4];
#pragma unroll
    for (int mi = 0; mi < 4; mi++)
      af[mi] = *(const f16x8_t*)(Asm + (wr * 64 + mi * 16 + l15) * 32 + kchunk);
#pragma unroll
    for (int ni = 0; ni < 8; ni++) {
      f16x8_t bfv =
          *(const f16x8_t*)(Bsm + (wc * 128 + ni * 16 + l15) * 32 + kchunk);
#pragma unroll
      for (int mi = 0; mi < 4; mi++)
        acc[mi][ni] = __builtin_amdgcn_mfma_f32_16x16x32_f16(
            af[mi], bfv, acc[mi][ni], 0, 0, 0);
    }
    __syncthreads();
  }

#pragma unroll
  for (int mi = 0; mi < 4; mi++) {
    const int mbase = m0 + wr * 64 + mi * 16 + l4 * 4;
#pragma unroll
    for (int ni = 0; ni < 8; ni++) {
      const int n = n0 + wc * 128 + ni * 16 + l15;
      if (n < NQTOK) {   // n == 1568 is the cls column
#pragma unroll
        for (int r = 0; r < 4; r++) {
          Out[((size_t)b * CDIM + mbase + r) * NSPX + n] =
              (f16)(acc[mi][ni][r] + bias[mbase + r]);
        }
      }
    }
  }
}

// ---------------------------------------------------------------------------
// Projection MFMA GEMM, same round-12 structure. 1D grid 300, bijective XCD
// swizzle (nwg=300: q=37, r=4).
// ---------------------------------------------------------------------------
__global__ __launch_bounds__(256, 2) void gemm_proj_f16_kernel(
    const f16* __restrict__ Wp16, const f16* __restrict__ o16,
    const float* __restrict__ bias, float* __restrict__ xo,
    float* __restrict__ cls_o) {
  __shared__ __align__(16) f16 Asm[128 * 32];
  __shared__ __align__(16) f16 Bsm[256 * 32];

  const int bid = blockIdx.x;
  const int xcd = bid & 7, pos_ = bid >> 3;
  const int base = (xcd < 4) ? xcd * 38 : 152 + (xcd - 4) * 37;
  const int wgid = base + pos_;
  const int m0 = (wgid / 50) * 128;
  const int n0 = (wgid % 50) * 256;
  const int tid = threadIdx.x;
  const int lane = tid & 63;
  const int w = tid >> 6;
  const int wr = w >> 1, wc = w & 1;
  const int l15 = lane & 15, l4 = lane >> 4;

  const int srow = lane >> 2;
  const int skq = ((lane & 3) ^ ((lane >> 3) & 3)) * 8;
  const f16* Ag = Wp16 + (size_t)(m0 + w * 32 + srow) * CDIM + skq;
  const f16* Bg = o16 + (size_t)(n0 + w * 64 + srow) * CDIM + skq;
  f16* lA = Asm + w * 32 * 32;
  f16* lB = Bsm + w * 64 * 32;

  const int rsw = (l15 >> 1) & 3;
  const int kchunk = (l4 ^ rsw) * 8;

  f32x4_t acc[4][8];
#pragma unroll
  for (int i = 0; i < 4; i++)
#pragma unroll
    for (int j = 0; j < 8; j++) acc[i][j] = (f32x4_t){0.f, 0.f, 0.f, 0.f};

  for (int k0 = 0; k0 < CDIM; k0 += 32) {
    gld_lds16(Ag + k0, lA);
    gld_lds16(Ag + 16 * CDIM + k0, lA + 16 * 32);
    gld_lds16(Bg + k0, lB);
    gld_lds16(Bg + 16 * CDIM + k0, lB + 16 * 32);
    gld_lds16(Bg + 32 * CDIM + k0, lB + 32 * 32);
    gld_lds16(Bg + 48 * CDIM + k0, lB + 48 * 32);
    __syncthreads();
    f16x8_t af[4];
#pragma unroll
    for (int mi = 0; mi < 4; mi++)
      af[mi] = *(const f16x8_t*)(Asm + (wr * 64 + mi * 16 + l15) * 32 + kchunk);
#pragma unroll
    for (int ni = 0; ni < 8; ni++) {
      f16x8_t bfv =
          *(const f16x8_t*)(Bsm + (wc * 128 + ni * 16 + l15) * 32 + kchunk);
#pragma unroll
      for (int mi = 0; mi < 4; mi++)
        acc[mi][ni] = __builtin_amdgcn_mfma_f32_16x16x32_f16(
            af[mi], bfv, acc[mi][ni], 0, 0, 0);
    }
    __syncthreads();
  }

#pragma unroll
  for (int ni = 0; ni < 8; ni++) {
    const int tok = n0 + wc * 128 + ni * 16 + l15;
    if (tok < MTOK) {
      const int bb = tok / NQTOK;
      const int nn = tok % NQTOK;
#pragma unroll
      for (int mi = 0; mi < 4; mi++) {
        const int mbase = m0 + wr * 64 + mi * 16 + l4 * 4;
#pragma unroll
        for (int r = 0; r < 4; r++) {
          float v = acc[mi][ni][r] + bias[mbase + r];
          if (nn == 0)
            cls_o[bb * CDIM + mbase + r] = v;
          else
            xo[((size_t)bb * CDIM + mbase + r) * (size_t)NSP + nn - 1] = v;
        }
      }
    }
  }
}

// ---------------------------------------------------------------------------
// Depthwise conv for q (stride 1, out 8x14x14). One block per (b,c) plane.
// L-fastest padded LDS volume (round-12 verified).
// ---------------------------------------------------------------------------
__global__ __launch_bounds__(256) void dwconv_q_kernel(
    const f16* __restrict__ q_lin, const float* __restrict__ cq,
    f16* __restrict__ q_pool) {
  __shared__ float vol[16 * 196];   // 12,544 B
  __shared__ float wsm[27];
  const int c = blockIdx.x % CDIM;
  const int b = blockIdx.x / CDIM;
  const f16* xb = q_lin + ((size_t)b * CDIM + c) * (size_t)NSPX;

  for (int i = threadIdx.x; i < 16 * 196; i += 256) vol[i] = 0.f;
  if (threadIdx.x < 27) wsm[threadIdx.x] = cq[c * 27 + threadIdx.x];
  __syncthreads();
  for (int i = threadIdx.x; i < NSP; i += 256) {
    int li = i / 196;
    int r = i - li * 196;
    int hi = r / 14;
    int wi = r - hi * 14;
    vol[(wi + 1) * 196 + (hi + 1) * 12 + (li + 1)] = (float)xb[i];
  }
  __syncthreads();

  if (threadIdx.x < 196) {
    const int ho = threadIdx.x / 14;
    const int wo = threadIdx.x - ho * 14;
    float sums[8];
#pragma unroll
    for (int lo = 0; lo < 8; lo++) sums[lo] = 0.f;
#pragma unroll
    for (int kh = 0; kh < 3; kh++) {
#pragma unroll
      for (int kw = 0; kw < 3; kw++) {
        const float* p = &vol[(wo + kw) * 196 + (ho + kh) * 12];
        float z[10];
        *(f32x4_t*)&z[0] = *(const f32x4_t*)p;
        *(f32x4_t*)&z[4] = *(const f32x4_t*)(p + 4);
        *(f32x2_t*)&z[8] = *(const f32x2_t*)(p + 8);
        const float w0 = wsm[0 + kh * 3 + kw];
        const float w1 = wsm[9 + kh * 3 + kw];
        const float w2 = wsm[18 + kh * 3 + kw];
#pragma unroll
        for (int lo = 0; lo < 8; lo++) {
          sums[lo] = fmaf(z[lo], w0, sums[lo]);
          sums[lo] = fmaf(z[lo + 1], w1, sums[lo]);
          sums[lo] = fmaf(z[lo + 2], w2, sums[lo]);
        }
      }
    }
    f16* ob = q_pool + ((size_t)b * CDIM + c) * (size_t)NSP;
    const int hw = ho * 14 + wo;
#pragma unroll
    for (int lo = 0; lo < 8; lo++) ob[lo * 196 + hw] = (f16)sums[lo];
  }
}

// ---------------------------------------------------------------------------
// Depthwise conv for k/v (stride 2, out 8x7x7). 4 channels per block.
// ---------------------------------------------------------------------------
__global__ __launch_bounds__(256) void dwconv_kv_kernel(
    const f16* __restrict__ k_lin, const f16* __restrict__ v_lin,
    const float* __restrict__ ck, const float* __restrict__ cv,
    f16* __restrict__ k_pool, f16* __restrict__ v_pool) {
  __shared__ float vol4[4][16 * 196];   // 50,176 B
  __shared__ float wsm4[4][27];
  const int which = blockIdx.y;
  const f16* X = which ? v_lin : k_lin;
  const float* wconv = which ? cv : ck;
  f16* Out = which ? v_pool : k_pool;
  const int cg = blockIdx.x % (CDIM / 4);
  const int b = blockIdx.x / (CDIM / 4);
  const int c0 = cg * 4;
  const f16* xb0 = X + ((size_t)b * CDIM + c0) * (size_t)NSPX;

  for (int i = threadIdx.x; i < 4 * 16 * 196; i += 256)
    ((float*)vol4)[i] = 0.f;
  if (threadIdx.x < 108) {
    int ch = threadIdx.x / 27;
    int j = threadIdx.x - ch * 27;
    wsm4[ch][j] = wconv[(c0 + ch) * 27 + j];
  }
  __syncthreads();
  for (int i = threadIdx.x; i < 4 * NSP; i += 256) {
    int ch = i / NSP;
    int j = i - ch * NSP;
    int li = j / 196;
    int r = j - li * 196;
    int hi = r / 14;
    int wi = r - hi * 14;
    vol4[ch][(wi + 1) * 196 + (hi + 1) * 12 + (li + 1)] =
        (float)xb0[(size_t)ch * NSPX + j];
  }
  __syncthreads();

  if (threadIdx.x < 196) {
    const int ch = threadIdx.x / 49;
    const int p2 = threadIdx.x - ch * 49;
    const int ho = p2 / 7;
    const int wo = p2 - ho * 7;
    const float* vol = vol4[ch];
    const float* wsm = wsm4[ch];
    float sums[8];
#pragma unroll
    for (int lo = 0; lo < 8; lo++) sums[lo] = 0.f;
#pragma unroll
    for (int kh = 0; kh < 3; kh++) {
#pragma unroll
      for (int kw = 0; kw < 3; kw++) {
        const float* p = &vol[(wo * 2 + kw) * 196 + (ho * 2 + kh) * 12];
        float z[10];
        *(f32x4_t*)&z[0] = *(const f32x4_t*)p;
        *(f32x4_t*)&z[4] = *(const f32x4_t*)(p + 4);
        *(f32x2_t*)&z[8] = *(const f32x2_t*)(p + 8);
        const float w0 = wsm[0 + kh * 3 + kw];
        const float w1 = wsm[9 + kh * 3 + kw];
        const float w2 = wsm[18 + kh * 3 + kw];
#pragma unroll
        for (int lo = 0; lo < 8; lo++) {
          sums[lo] = fmaf(z[lo], w0, sums[lo]);
          sums[lo] = fmaf(z[lo + 1], w1, sums[lo]);
          sums[lo] = fmaf(z[lo + 2], w2, sums[lo]);
        }
      }
    }
    f16* ob = Out + ((size_t)b * CDIM + c0 + ch) * (size_t)NKSP;
    const int hw = ho * 7 + wo;
#pragma unroll
    for (int lo = 0; lo < 8; lo++) ob[lo * 49 + hw] = (f16)sums[lo];
  }
}

// ---------------------------------------------------------------------------
// Fused LayerNorm + head-pack for q AND k + cls rows, one launch:
// grid (63, B); bx<49 -> q tile, bx<62 -> k tile, bx==62 -> cls fill.
// (validated in round 15)
// ---------------------------------------------------------------------------
__global__ __launch_bounds__(256) void ln_pack_qk2_kernel(
    const f16* __restrict__ qp, const f16* __restrict__ kp,
    const f16* __restrict__ qlin, const f16* __restrict__ klin,
    const float* __restrict__ lnq_w, const float* __restrict__ lnq_b,
    const float* __restrict__ lnk_w, const float* __restrict__ lnk_b,
    f16* __restrict__ Qh, f16* __restrict__ Kh) {
  const int bx = blockIdx.x;
  const int b = blockIdx.y;
  const int tid = threadIdx.x;

  if (bx == 62) {   // cls fill: t=0 rows of Qh/Kh from lin cls column
#pragma unroll
    for (int cc = 0; cc < 3; cc++) {
      const int c = tid + cc * 256;
      Qh[(((size_t)(b * NHEADS + (c >> 6))) * TQP) * 64 + (c & 63)] =
          qlin[((size_t)b * CDIM + c) * NSPX + NSP];
      Kh[(((size_t)(b * NHEADS + (c >> 6))) * TKP) * 64 + (c & 63)] =
          klin[((size_t)b * CDIM + c) * NSPX + NSP];
    }
    return;
  }

  const bool isq = bx < 49;
  const f16* xp = isq ? qp : kp;
  const float* ln_w = isq ? lnq_w : lnk_w;
  const float* ln_b = isq ? lnq_b : lnk_b;
  f16* OutH = isq ? Qh : Kh;
  const int np = isq ? NSP : NKSP;
  const int tp = isq ? TQP : TKP;
  const int p0 = (isq ? bx : bx - 49) * 32;
  const int pl = tid & 31;
  const int grp = tid >> 5;
  const int pos = p0 + pl;
  const bool act = pos < np;
  const f16* Xb = xp + (size_t)b * CDIM * (size_t)np;

  __shared__ __align__(16) f16 tile[32][784];
  __shared__ float r1[8][33], r2[8][33];
  __shared__ float smean[32], srstd[32];

  const int swz = (pl & 7) << 3;
  float s1 = 0.f, s2 = 0.f;
  for (int cc = 0; cc < 12; cc++) {
    const int c0 = grp * 96 + cc * 8;
    f16x8_t hv;
#pragma unroll
    for (int i = 0; i < 8; i++) {
      f16 h = act ? Xb[(size_t)(c0 + i) * np + pos] : (f16)0.f;
      hv[i] = h;
      float v = (float)h;
      s1 += v;
      s2 = fmaf(v, v, s2);
    }
    *(f16x8_t*)&tile[pl][c0 ^ swz] = hv;
  }
  r1[grp][pl] = s1;
  r2[grp][pl] = s2;
  __syncthreads();
  if (tid < 32) {
    float t1 = 0.f, t2 = 0.f;
#pragma unroll
    for (int g = 0; g < 8; g++) { t1 += r1[g][tid]; t2 += r2[g][tid]; }
    float mean = t1 * (1.f / 768.f);
    float var = t2 * (1.f / 768.f) - mean * mean;
    smean[tid] = mean;
    srstd[tid] = rsqrtf(var + LN_EPS);
  }
  __syncthreads();

  const int tl = tid >> 3, d8 = (tid & 7) * 8;
  const float mean = smean[tl], rstd = srstd[tl];
  const bool wv = (p0 + tl) < np;
  const int tswz = (tl & 7) << 3;
#pragma unroll
  for (int h = 0; h < NHEADS; h++) {
    const int c = h * 64 + d8;
    f16x8_t raw = *(const f16x8_t*)&tile[tl][c ^ tswz];
    float4 w1 = *(const float4*)&ln_w[c];
    float4 w2 = *(const float4*)&ln_w[c + 4];
    float4 b1 = *(const float4*)&ln_b[c];
    float4 b2 = *(const float4*)&ln_b[c + 4];
    f16x8_t ov;
    ov[0] = (f16)(((float)raw[0] - mean) * rstd * w1.x + b1.x);
    ov[1] = (f16)(((float)raw[1] - mean) * rstd * w1.y + b1.y);
    ov[2] = (f16)(((float)raw[2] - mean) * rstd * w1.z + b1.z);
    ov[3] = (f16)(((float)raw[3] - mean) * rstd * w1.w + b1.w);
    ov[4] = (f16)(((float)raw[4] - mean) * rstd * w2.x + b2.x);
    ov[5] = (f16)(((float)raw[5] - mean) * rstd * w2.y + b2.y);
    ov[6] = (f16)(((float)raw[6] - mean) * rstd * w2.z + b2.z);
    ov[7] = (f16)(((float)raw[7] - mean) * rstd * w2.w + b2.w);
    if (wv)
      *(uint4*)(OutH +
                (((size_t)(b * NHEADS + h)) * (size_t)tp + (p0 + tl + 1)) * 64 +
                d8) = *(uint4*)&ov;
  }
}

// ---------------------------------------------------------------------------
// Fused LayerNorm + transpose-pack for v. cls (t=0) raw from v_lin col NSP.
// ---------------------------------------------------------------------------
__global__ __launch_bounds__(256) void ln_pack_v_kernel(
    const f16* __restrict__ vp, const f16* __restrict__ vlin,
    const float* __restrict__ ln_w, const float* __restrict__ ln_b,
    f16* __restrict__ Vht) {
  const int b = blockIdx.y;
  const int t0 = blockIdx.x * 32;
  const int tid = threadIdx.x;
  const int pl = tid & 31;
  const int grp = tid >> 5;
  const int t = t0 + pl;
  const int pos = t - 1;
  const bool isv = (t >= 1) && (t < NKTOK);
  const f16* Vb = vp + (size_t)b * CDIM * (size_t)NKSP;

  __shared__ float r1[8][33], r2[8][33];
  __shared__ float smean[32], srstd[32];
  __shared__ __align__(16) f16 vtile[128][40];

  float s1 = 0.f, s2 = 0.f;
  if (isv) {
    for (int c = grp; c < CDIM; c += 8) {
      float v = (float)Vb[(size_t)c * NKSP + pos];
      s1 += v;
      s2 = fmaf(v, v, s2);
    }
  }
  r1[grp][pl] = s1;
  r2[grp][pl] = s2;
  __syncthreads();
  if (tid < 32) {
    float t1 = 0.f, t2 = 0.f;
#pragma unroll
    for (int g = 0; g < 8; g++) { t1 += r1[g][tid]; t2 += r2[g][tid]; }
    float mean = t1 * (1.f / 768.f);
    float var = t2 * (1.f / 768.f) - mean * mean;
    smean[tid] = mean;
    srstd[tid] = rsqrtf(var + LN_EPS);
  }
  __syncthreads();
  const float mean = smean[pl], rstd = srstd[pl];

  for (int cc = 0; cc < 6; cc++) {
#pragma unroll
    for (int i = 0; i < 16; i++) {
      int cl = grp * 16 + i;
      int c = cc * 128 + cl;
      float outv;
      if (isv)
        outv = ((float)Vb[(size_t)c * NKSP + pos] - mean) * rstd * ln_w[c] +
               ln_b[c];
      else if (t == 0)
        outv = (float)vlin[((size_t)b * CDIM + c) * NSPX + NSP];
      else
        outv = 0.f;
      vtile[cl][pl] = (f16)outv;
    }
    __syncthreads();
#pragma unroll
    for (int it = 0; it < 2; it++) {
      int idx = it * 256 + tid;
      int cl = idx >> 2, t8 = (idx & 3) * 8;
      uint4 vv = *(const uint4*)&vtile[cl][t8];
      *(uint4*)(Vht + ((size_t)b * CDIM + cc * 128 + cl) * (size_t)TKP + t0 +
                t8) = vv;
    }
    __syncthreads();
  }
}

// ---------------------------------------------------------------------------
// MFMA flash attention. Grid (7, 12, 8), 256 threads = 4 waves; wave tile
// 64 q x 64 keys (bq[4][2], sacc[4][4], oacc[4][4]).
// ---------------------------------------------------------------------------
__global__ __launch_bounds__(256) void attn_mfma_kernel(
    const f16* __restrict__ Qh, const f16* __restrict__ Kh,
    const f16* __restrict__ Vht, f16* __restrict__ o16) {
  __shared__ __align__(16) f16 Ks[64 * 72];   // [key][d], pad 8
  __shared__ __align__(16) f16 Vt[64 * 72];   // [d][key], pad 8
  const int qt = blockIdx.x, h = blockIdx.y, b = blockIdx.z;
  const int tid = threadIdx.x;
  const int lane = tid & 63;
  const int w = tid >> 6;
  const int l15 = lane & 15, l4 = lane >> 4;
  const int q0 = qt * 256 + w * 64;

  const f16* Qp = Qh + ((size_t)(b * NHEADS + h) * TQP) * 64;
  const f16* Kp = Kh + ((size_t)(b * NHEADS + h) * TKP) * 64;
  const f16* Vp = Vht + ((size_t)(b * NHEADS + h) * 64) * TKP;

  f16x8_t bq[4][2];
#pragma unroll
  for (int qi = 0; qi < 4; qi++)
#pragma unroll
    for (int kf = 0; kf < 2; kf++)
      bq[qi][kf] = *(const f16x8_t*)(Qp + (size_t)(q0 + qi * 16 + l15) * 64 +
                                     kf * 32 + l4 * 8);

  f32x4_t oacc[4][4];
#pragma unroll
  for (int df = 0; df < 4; df++)
#pragma unroll
    for (int qi = 0; qi < 4; qi++) oacc[df][qi] = (f32x4_t){0.f, 0.f, 0.f, 0.f};
  float mrow[4] = {-1e30f, -1e30f, -1e30f, -1e30f};
  float lrow[4] = {0.f, 0.f, 0.f, 0.f};

  const int sr = tid >> 2, sc = (tid & 3) * 16;

  for (int kv0 = 0; kv0 < TKP; kv0 += 64) {
    const f16* kg = Kp + (size_t)(kv0 + sr) * 64 + sc;
    uint4 kl0 = *(const uint4*)kg;
    uint4 kl1 = *(const uint4*)(kg + 8);
    const f16* vg = Vp + (size_t)sr * TKP + kv0 + sc;
    uint4 vl0 = *(const uint4*)vg;
    uint4 vl1 = *(const uint4*)(vg + 8);
    __syncthreads();
    *(uint4*)(Ks + sr * 72 + sc) = kl0;
    *(uint4*)(Ks + sr * 72 + sc + 8) = kl1;
    *(uint4*)(Vt + sr * 72 + sc) = vl0;
    *(uint4*)(Vt + sr * 72 + sc + 8) = vl1;
    __syncthreads();

    // ---- S^T = K * Q^T ----
    f32x4_t sacc[4][4];
#pragma unroll
    for (int ki = 0; ki < 4; ki++)
#pragma unroll
      for (int qi = 0; qi < 4; qi++)
        sacc[ki][qi] = (f32x4_t){0.f, 0.f, 0.f, 0.f};
#pragma unroll
    for (int kf = 0; kf < 2; kf++) {
#pragma unroll
      for (int ki = 0; ki < 4; ki++) {
        f16x8_t ak =
            *(const f16x8_t*)(Ks + (ki * 16 + l15) * 72 + kf * 32 + l4 * 8);
#pragma unroll
        for (int qi = 0; qi < 4; qi++)
          sacc[ki][qi] = __builtin_amdgcn_mfma_f32_16x16x32_f16(
              ak, bq[qi][kf], sacc[ki][qi], 0, 0, 0);
      }
    }

    // ---- scale + mask + online softmax ----
    float pmax[4] = {-1e30f, -1e30f, -1e30f, -1e30f};
#pragma unroll
    for (int ki = 0; ki < 4; ki++) {
      const int keyb = kv0 + ki * 16 + l4 * 4;
#pragma unroll
      for (int qi = 0; qi < 4; qi++) {
#pragma unroll
        for (int rr = 0; rr < 4; rr++) {
          float s = sacc[ki][qi][rr] * ATTN_SCALE;
          if (keyb + rr >= NKTOK) s = -1e30f;
          sacc[ki][qi][rr] = s;
          pmax[qi] = fmaxf(pmax[qi], s);
        }
      }
    }
#pragma unroll
    for (int qi = 0; qi < 4; qi++) {
      pmax[qi] = fmaxf(pmax[qi], __shfl_xor(pmax[qi], 16, 64));
      pmax[qi] = fmaxf(pmax[qi], __shfl_xor(pmax[qi], 32, 64));
      float mnew = fmaxf(mrow[qi], pmax[qi]);
      float alpha = __expf(mrow[qi] - mnew);
      mrow[qi] = mnew;
      lrow[qi] *= alpha;
#pragma unroll
      for (int df = 0; df < 4; df++) {
        oacc[df][qi][0] *= alpha;
        oacc[df][qi][1] *= alpha;
        oacc[df][qi][2] *= alpha;
        oacc[df][qi][3] *= alpha;
      }
    }

    // ---- per-ki P + PV ----
#pragma unroll
    for (int ki = 0; ki < 4; ki++) {
      f16x4_t pb[4];
#pragma unroll
      for (int qi = 0; qi < 4; qi++) {
        float p0 = __expf(sacc[ki][qi][0] - mrow[qi]);
        float p1 = __expf(sacc[ki][qi][1] - mrow[qi]);
        float p2 = __expf(sacc[ki][qi][2] - mrow[qi]);
        float p3 = __expf(sacc[ki][qi][3] - mrow[qi]);
        lrow[qi] += p0 + p1 + p2 + p3;
        f16x4_t pv = {(f16)p0, (f16)p1, (f16)p2, (f16)p3};
        pb[qi] = pv;
      }
#pragma unroll
      for (int df = 0; df < 4; df++) {
        f16x4_t av =
            *(const f16x4_t*)(Vt + (df * 16 + l15) * 72 + ki * 16 + l4 * 4);
#pragma unroll
        for (int qi = 0; qi < 4; qi++)
          oacc[df][qi] = __builtin_amdgcn_mfma_f32_16x16x16f16(
              av, pb[qi], oacc[df][qi], 0, 0, 0);
      }
    }
  }

  float inv[4];
#pragma unroll
  for (int qi = 0; qi < 4; qi++) {
    float l = lrow[qi];
    l += __shfl_xor(l, 16, 64);
    l += __shfl_xor(l, 32, 64);
    inv[qi] = 1.f / l;
  }
#pragma unroll
  for (int qi = 0; qi < 4; qi++) {
    const int q = q0 + qi * 16 + l15;
    if (q < NQTOK) {
      f16* op = o16 + ((size_t)(b * NQTOK + q)) * CDIM + h * 64 + l4 * 4;
#pragma unroll
      for (int df = 0; df < 4; df++) {
        f16x4_t ov = {(f16)(oacc[df][qi][0] * inv[qi]),
                      (f16)(oacc[df][qi][1] * inv[qi]),
                      (f16)(oacc[df][qi][2] * inv[qi]),
                      (f16)(oacc[df][qi][3] * inv[qi])};
        *(f16x4_t*)(op + df * 16) = ov;
      }
    }
  }
}

// ---------------------------------------------------------------------------
extern "C" void kernel_launch(void* const* d_in, const int* in_sizes, int n_in,
                              void* d_out, int out_size, void* d_ws, size_t ws_size,
                              hipStream_t stream) {
  const float* x      = (const float*)d_in[0];
  const float* cls    = (const float*)d_in[1];
  const float* Wq     = (const float*)d_in[2];
  const float* bq     = (const float*)d_in[3];
  const float* Wk     = (const float*)d_in[4];
  const float* bk     = (const float*)d_in[5];
  const float* Wv     = (const float*)d_in[6];
  const float* bv     = (const float*)d_in[7];
  const float* conv_q = (const float*)d_in[8];
  const float* conv_k = (const float*)d_in[9];
  const float* conv_v = (const float*)d_in[10];
  const float* lnq_w  = (const float*)d_in[11];
  const float* lnq_b  = (const float*)d_in[12];
  const float* lnk_w  = (const float*)d_in[13];
  const float* lnk_b  = (const float*)d_in[14];
  const float* lnv_w  = (const float*)d_in[15];
  const float* lnv_b  = (const float*)d_in[16];
  const float* Wproj  = (const float*)d_in[17];
  const float* bproj  = (const float*)d_in[18];

  // Workspace layout (bytes). Total = 124,747,776 B ≈ 124.7 MB.
  char* wsb = (char*)d_ws;
  f16*   Xt     = (f16*)(wsb + 0);           // 8*1792*768*2 = 22,020,096
  f16*   W16    = (f16*)(wsb + 22020096);    //  4,718,592
  f16*   q_lin  = (f16*)(wsb + 26738688);    // 8*768*1576*2 = 19,365,888
  f16*   k_lin  = (f16*)(wsb + 46104576);    // 19,365,888
  f16*   v_lin  = (f16*)(wsb + 65470464);    // 19,365,888
  f16*   k_pool = (f16*)(wsb + 84836352);    //  4,816,896
  f16*   v_pool = (f16*)(wsb + 89653248);    //  4,816,896
  f16*   Kh     = (f16*)(wsb + 94470144);    //  5,505,024
  f16*   Vht    = (f16*)(wsb + 99975168);    //  5,505,024
  f16*   q_pool = (f16*)(wsb + 105480192);   // 19,267,584 -> end 124,747,776
  f16*   Qh     = Xt;      // alias: Xt dead after QKV GEMM (sizes equal)
  f16*   o16    = v_lin;   // alias: v_lin (+294KB of dead k_pool) at proj;
                           // attn writes only rows < 12552

  f16* W16p = W16 + (size_t)3 * WELEM;

  // 1. convert weights to fp16
  convert4_kernel<<<dim3(576, 4), 256, 0, stream>>>(Wq, Wk, Wv, Wproj, W16);

  // 2. transpose+convert X (+cls as row 1568) -> Xt
  transpose_x_kernel<<<dim3(56, 24, BATCH), 256, 0, stream>>>(x, cls, Xt);

  // 3. fused QKV MFMA GEMM (round-12 structure) -> f16 lin buffers
  gemm_qkv_f16_kernel<<<1008, 256, 0, stream>>>(W16, Xt, bq, bk, bv, q_lin);

  // 4. depthwise convs (q stride-1; k/v stride-2, 4 ch/block)
  dwconv_q_kernel<<<BATCH * CDIM, 256, 0, stream>>>(q_lin, conv_q, q_pool);
  dwconv_kv_kernel<<<dim3(BATCH * CDIM / 4, 2), 256, 0, stream>>>(
      k_lin, v_lin, conv_k, conv_v, k_pool, v_pool);

  // 5. fused LN + pack (q, k, and cls rows in one launch; v separate)
  ln_pack_qk2_kernel<<<dim3(63, BATCH), 256, 0, stream>>>(
      q_pool, k_pool, q_lin, k_lin, lnq_w, lnq_b, lnk_w, lnk_b, Qh, Kh);
  ln_pack_v_kernel<<<dim3(14, BATCH), 256, 0, stream>>>(v_pool, v_lin, lnv_w,
                                                        lnv_b, Vht);

  // 6. MFMA attention (64-q wave tiles) -> o16
  attn_mfma_kernel<<<dim3(7, NHEADS, BATCH), 256, 0, stream>>>(Qh, Kh, Vht,
                                                               o16);

  // 7. projection MFMA GEMM -> d_out
  float* xo = (float*)d_out;
  float* cls_o = (float*)d_out + (size_t)BATCH * CDIM * NSP;
  gemm_proj_f16_kernel<<<300, 256, 0, stream>>>(W16p, o16, bproj, xo, cls_o);
}